// Round 11
// baseline (419.595 us; speedup 1.0000x reference)
//
#include <hip/hip_runtime.h>
#include <hip/hip_bf16.h>
#include <stdint.h>

#define BB 2
#define SB 2048
#define DD 512
#define HH 4
#define VV 32000

typedef __attribute__((ext_vector_type(4))) float f32x4;
typedef __attribute__((ext_vector_type(8))) short bf16x8;
typedef __attribute__((ext_vector_type(4))) unsigned short us4;

__device__ __forceinline__ unsigned short f2bf(float f) {
    unsigned u = __float_as_uint(f);
    u += 0x7fffu + ((u >> 16) & 1u);
    return (unsigned short)(u >> 16);
}

__device__ __forceinline__ __attribute__((address_space(3))) unsigned int*
as_lds(void* p) {
    return (__attribute__((address_space(3))) unsigned int*)(unsigned)(uintptr_t)p;
}
__device__ __forceinline__ const __attribute__((address_space(1))) unsigned int*
as_gbl(const void* p) {
    return (const __attribute__((address_space(1))) unsigned int*)(uintptr_t)p;
}

// swizzled read from a [rows][64] bf16 LDS tile (128B rows): logical 16B-chunk c
// lives at slot c^(row&7).
__device__ __forceinline__ bf16x8 ldsrd64(const unsigned short* base, int row, int c) {
    return *(const bf16x8*)((const char*)base + row * 128 + ((c ^ (row & 7)) << 4));
}

// ---------------- merged prep kernel ----------------
__global__ void k_prep(const int* __restrict__ ids, const float* __restrict__ tbl,
                       const float* __restrict__ als,
                       const float* __restrict__ fw, const float* __restrict__ ow,
                       unsigned short* __restrict__ outw_bf, unsigned short* __restrict__ fusw_bf,
                       unsigned short* __restrict__ emb, unsigned short* __restrict__ embT,
                       float* __restrict__ dtab, float* __restrict__ lsum)
{
    __shared__ unsigned short TT[64][72];
    const int bid = blockIdx.x, t = threadIdx.x;

    if (bid < 2000) {
        int base = bid * 8192 + t * 4;
#pragma unroll
        for (int it = 0; it < 8; ++it) {
            int i = base + it * 1024;
            float4 v = *(const float4*)(ow + i);
            us4 o; o.x = f2bf(v.x); o.y = f2bf(v.y); o.z = f2bf(v.z); o.w = f2bf(v.w);
            *(us4*)(outw_bf + i) = o;
        }
    } else if (bid < 2256) {
        int base = (bid - 2000) * 4096 + t * 4;
#pragma unroll
        for (int it = 0; it < 4; ++it) {
            int i = base + it * 1024;
            float4 v = *(const float4*)(fw + i);
            us4 o; o.x = f2bf(v.x); o.y = f2bf(v.y); o.z = f2bf(v.z); o.w = f2bf(v.w);
            *(us4*)(fusw_bf + i) = o;
        }
    } else if (bid < 6352) {
        int row = bid - 2256;
        int id = ids[row];
        if (id < 0) id = 0;
        if (id >= VV) id = VV - 1;
        const float* s = tbl + (size_t)id * DD;
        unsigned short* d = emb + (size_t)row * DD;
        d[t]       = f2bf(s[t]);
        d[t + 256] = f2bf(s[t + 256]);
    } else if (bid < 6448) {
        int i = (bid - 6352) * 256 + t;
        if (i < HH * SB) {
            int h = i >> 11, dd = i & (SB - 1);
            dtab[i] = 0.04419417382415922f / (1.f + als[h] * (float)dd);
        } else {
            lsum[i - HH * SB] = 0.f;
        }
    } else {
        int bid2 = bid - 6448;
        const int d0 = (bid2 & 7) * 64, s0 = ((bid2 >> 3) & 31) * 64, b = bid2 >> 8;
        {
            int s = t >> 2, c16 = (t & 3) * 16;
            int id = ids[b * SB + s0 + s];
            if (id < 0) id = 0;
            if (id >= VV) id = VV - 1;
            const float* src = tbl + (size_t)id * DD + d0 + c16;
#pragma unroll
            for (int q4 = 0; q4 < 4; ++q4) {
                float4 v = *(const float4*)(src + q4 * 4);
                TT[c16 + q4 * 4 + 0][s] = f2bf(v.x);
                TT[c16 + q4 * 4 + 1][s] = f2bf(v.y);
                TT[c16 + q4 * 4 + 2][s] = f2bf(v.z);
                TT[c16 + q4 * 4 + 3][s] = f2bf(v.w);
            }
        }
        __syncthreads();
        {
            int d = t >> 2, sc = (t & 3) * 16;
            bf16x8 o0, o1;
#pragma unroll
            for (int j = 0; j < 8; ++j) {
                o0[j] = (short)TT[d][sc + j];
                o1[j] = (short)TT[d][sc + 8 + j];
            }
            unsigned short* dst = embT + ((size_t)(b * DD + d0 + d)) * SB + s0 + sc;
            *(bf16x8*)dst = o0;
            *(bf16x8*)(dst + 8) = o1;
        }
    }
}

// ---------------- phase 2: shared base QK^T -> per-head P tiles + row sums ----------------
__launch_bounds__(256, 2)
__global__ void k_base(const unsigned short* __restrict__ emb,
                       const unsigned char* __restrict__ pad,
                       const float* __restrict__ sfs,
                       const float* __restrict__ dtab,
                       unsigned short* __restrict__ P,      // [4][2][2048][2048]
                       float* __restrict__ lsum)            // [4][2][2048]
{
    const int kt = blockIdx.x, qt = blockIdx.y, b = blockIdx.z;
    if (kt > qt + 1) return;
    const int tid = threadIdx.x, lane = tid & 63, wv = tid >> 6;
    const int l15 = lane & 15, g = lane >> 4;

    if (kt == qt + 1) {
        int row = tid >> 2, cb = (tid & 3) * 16;
        int4 z = {0, 0, 0, 0};
#pragma unroll
        for (int h = 0; h < 4; ++h) {
            unsigned short* Ph = P + (((size_t)(h * 2 + b)) * SB + qt * 64 + row) * SB + kt * 64 + cb;
            *(int4*)Ph = z;
            *(int4*)(Ph + 8) = z;
        }
        return;
    }

    __shared__ __align__(16) unsigned short Ql[64 * 128];
    __shared__ __align__(16) unsigned short Kl[64 * 128];

    const int q = qt * 64 + wv * 16 + l15;

    f32x4 zero4 = {0.f, 0.f, 0.f, 0.f};
    f32x4 cc[4];
#pragma unroll
    for (int c = 0; c < 4; ++c) cc[c] = zero4;

    for (int dc = 0; dc < 4; ++dc) {
        const int d0 = dc * 128;
        __syncthreads();
#pragma unroll
        for (int i = 0; i < 4; ++i) {
            int flat = (i * 256 + tid) * 8;
            int row = flat >> 7;
            int ch  = (flat >> 3) & 15;
            int scol = ((ch ^ (row & 15)) << 3);
            __builtin_amdgcn_global_load_lds(
                as_gbl(emb + ((size_t)(b * SB + qt * 64 + row)) * DD + d0 + scol),
                as_lds(Ql + flat), 16, 0, 0);
            __builtin_amdgcn_global_load_lds(
                as_gbl(emb + ((size_t)(b * SB + kt * 64 + row)) * DD + d0 + scol),
                as_lds(Kl + flat), 16, 0, 0);
        }
        asm volatile("s_waitcnt vmcnt(0)" ::: "memory");
        __syncthreads();

#pragma unroll
        for (int dsl = 0; dsl < 4; ++dsl) {
            int chr = (dsl * 4 + g);
            bf16x8 qf = *(const bf16x8*)(Ql + (wv * 16 + l15) * 128 + ((chr ^ l15) << 3));
#pragma unroll
            for (int c = 0; c < 4; ++c) {
                bf16x8 kf = *(const bf16x8*)(Kl + (c * 16 + l15) * 128 + ((chr ^ l15) << 3));
                cc[c] = __builtin_amdgcn_mfma_f32_16x16x32_bf16(kf, qf, cc[c], 0, 0, 0);
            }
        }
    }

    unsigned long long padm = __ballot(pad[(size_t)b * SB + kt * 64 + lane] != 0);

    const int wins[4] = {1 << 30, 128, 512, 1 << 30};
#pragma unroll
    for (int h = 0; h < 4; ++h) {
        const int win = wins[h];
        if (kt * 64 + win + 192 < qt * 64) continue;
        const float sf = sfs[h];
        const float* dth = dtab + h * SB;
        float rsum = 0.f;
        unsigned short pb[4][4];
#pragma unroll
        for (int c = 0; c < 4; ++c) {
#pragma unroll
            for (int r = 0; r < 4; ++r) {
                int kk = kt * 64 + c * 16 + 4 * g + r;
                int dist = q - kk;
                float p = 0.f;
                if (dist >= 0 && dist <= win &&
                    ((dist == 0) || !((padm >> (c * 16 + 4 * g + r)) & 1ull))) {
                    float s = cc[c][r] * dth[dist];
                    if (dist == 0) s *= sf;
                    p = __expf(s);
                }
                rsum += p;
                pb[c][r] = f2bf(p);
            }
        }
        unsigned short* Ph = P + (((size_t)(h * 2 + b)) * SB + q) * SB + kt * 64;
#pragma unroll
        for (int c = 0; c < 4; ++c) {
            us4 o;
            o.x = pb[c][0]; o.y = pb[c][1]; o.z = pb[c][2]; o.w = pb[c][3];
            *(us4*)(Ph + c * 16 + 4 * g) = o;
        }
        rsum += __shfl_xor(rsum, 16, 64);
        rsum += __shfl_xor(rsum, 32, 64);
        if (lane < 16)
            atomicAdd(&lsum[((size_t)(h * 2 + b)) * SB + q], rsum);
    }
}

// ---------------- phase 3: ctx = P * V^T, normalize, write concat ----------------
__launch_bounds__(256, 2)
__global__ void k_pv(const unsigned short* __restrict__ P,
                     const unsigned short* __restrict__ embT,
                     const float* __restrict__ lsum,
                     unsigned short* __restrict__ concat)
{
    const int t64 = blockIdx.x, b = blockIdx.y, h = blockIdx.z;
    const int mt = t64 >> 2, nt = t64 & 3;
    const int Q0 = mt * 128;
    const int win = (h == 1) ? 128 : (h == 2) ? 512 : (1 << 30);
    int klo = Q0 - win - 64; if (klo < 0) klo = 0; klo &= ~63;
    const int khi = Q0 + 128;

    __shared__ __align__(16) unsigned short Al[128 * 32];
    __shared__ __align__(16) unsigned short Bl[128 * 32];

    const int tid = threadIdx.x, lane = tid & 63, wv = tid >> 6;
    const int wm = (wv >> 1) * 64, wn = (wv & 1) * 64;
    const int l15 = lane & 15, g = lane >> 4;

    f32x4 zero4 = {0.f, 0.f, 0.f, 0.f};
    f32x4 acc[4][4];
#pragma unroll
    for (int i = 0; i < 4; ++i)
#pragma unroll
        for (int j = 0; j < 4; ++j) acc[i][j] = zero4;

    const unsigned short* Ab = P + (((size_t)(h * 2 + b)) * SB + Q0) * SB;
    const unsigned short* Bb = embT + ((size_t)(b * DD + nt * 128)) * SB;

    for (int k0 = klo; k0 < khi; k0 += 32) {
        __syncthreads();
#pragma unroll
        for (int s = 0; s < 2; ++s) {
            int e = (s * 256 + tid) * 8;
            int row = e >> 5, col = e & 31;
            __builtin_amdgcn_global_load_lds(as_gbl(Ab + (size_t)row * SB + k0 + col),
                                             as_lds(Al + e), 16, 0, 0);
            __builtin_amdgcn_global_load_lds(as_gbl(Bb + (size_t)row * SB + k0 + col),
                                             as_lds(Bl + e), 16, 0, 0);
        }
        asm volatile("s_waitcnt vmcnt(0)" ::: "memory");
        __syncthreads();

        bf16x8 af[4], bfr[4];
#pragma unroll
        for (int i = 0; i < 4; ++i) {
            af[i]  = *(const bf16x8*)(Al + (wm + i * 16 + l15) * 32 + 8 * g);
            bfr[i] = *(const bf16x8*)(Bl + (wn + i * 16 + l15) * 32 + 8 * g);
        }
#pragma unroll
        for (int i = 0; i < 4; ++i)
#pragma unroll
            for (int j = 0; j < 4; ++j)
                acc[i][j] = __builtin_amdgcn_mfma_f32_16x16x32_bf16(af[i], bfr[j], acc[i][j], 0, 0, 0);
    }

    const float* ls = lsum + ((size_t)(h * 2 + b)) * SB;
    unsigned short* cb = concat + ((size_t)(b * SB)) * (HH * DD) + h * DD + nt * 128;
#pragma unroll
    for (int i = 0; i < 4; ++i) {
        int rowb = wm + i * 16 + g * 4;
        float inv[4];
#pragma unroll
        for (int rr = 0; rr < 4; ++rr) inv[rr] = 1.f / ls[Q0 + rowb + rr];
#pragma unroll
        for (int j = 0; j < 4; ++j) {
            int col = wn + j * 16 + l15;
#pragma unroll
            for (int rr = 0; rr < 4; ++rr)
                cb[(size_t)(Q0 + rowb + rr) * (HH * DD) + col] = f2bf(acc[i][j][rr] * inv[rr]);
        }
    }
}

// ---------------- m97-style 128x128 GEMM (fusion GEMM) ----------------
template <int OUTF32>
__launch_bounds__(256, 2)
__global__ void k_gemm_bt(const unsigned short* __restrict__ A,
                          const unsigned short* __restrict__ Bt,
                          const float* __restrict__ bias,
                          void* __restrict__ Cout,
                          int M, int N, int K)
{
    const int nMt = M >> 7;
    const int nwg = gridDim.x;
    int bid = blockIdx.x;
    int q = nwg >> 3, r = nwg & 7;
    int x = bid & 7, o = bid >> 3;
    int wg = (x < r ? x * (q + 1) : r * (q + 1) + (x - r) * q) + o;
    const int mt = wg % nMt, nt = wg / nMt;

    __shared__ __align__(16) unsigned short Al[128 * 32];
    __shared__ __align__(16) unsigned short Bl[128 * 32];

    const int tid = threadIdx.x;
    const int lane = tid & 63;
    const int wv = tid >> 6;
    const int wm = (wv >> 1) * 64, wn = (wv & 1) * 64;
    const int l15 = lane & 15, g = lane >> 4;

    f32x4 zero4 = {0.f, 0.f, 0.f, 0.f};
    f32x4 acc[4][4];
#pragma unroll
    for (int i = 0; i < 4; ++i)
#pragma unroll
        for (int j = 0; j < 4; ++j) acc[i][j] = zero4;

    const unsigned short* Ab = A + (size_t)mt * 128 * K;
    const unsigned short* Bb = Bt + (size_t)nt * 128 * K;

    for (int k0 = 0; k0 < K; k0 += 32) {
        __syncthreads();
#pragma unroll
        for (int s = 0; s < 2; ++s) {
            int e = (s * 256 + tid) * 8;
            int row = e >> 5, col = e & 31;
            __builtin_amdgcn_global_load_lds(as_gbl(Ab + (size_t)row * K + k0 + col),
                                             as_lds(Al + e), 16, 0, 0);
            __builtin_amdgcn_global_load_lds(as_gbl(Bb + (size_t)row * K + k0 + col),
                                             as_lds(Bl + e), 16, 0, 0);
        }
        asm volatile("s_waitcnt vmcnt(0)" ::: "memory");
        __syncthreads();

        bf16x8 af[4], bfr[4];
#pragma unroll
        for (int i = 0; i < 4; ++i) {
            af[i]  = *(const bf16x8*)(Al + (wm + i * 16 + l15) * 32 + 8 * g);
            bfr[i] = *(const bf16x8*)(Bl + (wn + i * 16 + l15) * 32 + 8 * g);
        }
#pragma unroll
        for (int i = 0; i < 4; ++i)
#pragma unroll
            for (int j = 0; j < 4; ++j)
                acc[i][j] = __builtin_amdgcn_mfma_f32_16x16x32_bf16(af[i], bfr[j], acc[i][j], 0, 0, 0);
    }

#pragma unroll
    for (int i = 0; i < 4; ++i) {
        int rowb = mt * 128 + wm + i * 16 + g * 4;
#pragma unroll
        for (int j = 0; j < 4; ++j) {
            int col = nt * 128 + wn + j * 16 + l15;
            float bv = bias[col];
            if (OUTF32) {
                float* C = (float*)Cout;
#pragma unroll
                for (int rr = 0; rr < 4; ++rr)
                    C[(size_t)(rowb + rr) * N + col] = acc[i][j][rr] + bv;
            } else {
                unsigned short* C = (unsigned short*)Cout;
#pragma unroll
                for (int rr = 0; rr < 4; ++rr)
                    C[(size_t)(rowb + rr) * N + col] = f2bf(acc[i][j][rr] + bv);
            }
        }
    }
}

// ---------------- logits GEMM v7: 256x256, BK=64 single-buffer, 64KB LDS, 2 blk/CU ----
// 512 thr = 8 waves (wr 2 x wc 4). 64 MFMA + 24 ds_read per wave between drains;
// cross-block TLP hides the per-step stage drain.
__launch_bounds__(512, 2)
__global__ void k_logits(const unsigned short* __restrict__ A,
                         const unsigned short* __restrict__ Bt,
                         const float* __restrict__ bias,
                         float* __restrict__ Cout,
                         int M, int N, int K)
{
    const int nMt = M >> 8;
    const int nwg = gridDim.x;
    int bid = blockIdx.x;
    int q = nwg >> 3, r = nwg & 7;
    int x = bid & 7, o = bid >> 3;
    int wg = (x < r ? x * (q + 1) : r * (q + 1) + (x - r) * q) + o;
    const int mt = wg % nMt, nt = wg / nMt;

    __shared__ __align__(16) char smem[66048];   // A [0,32K), B [32K,64K); epilogue 33KB

    const int tid = threadIdx.x, lane = tid & 63, wv = tid >> 6;
    const int wr = wv >> 2, wc = wv & 3;
    const int l15 = lane & 15, g = lane >> 4;

    f32x4 zero4 = {0.f, 0.f, 0.f, 0.f};
    f32x4 acc[8][4];
#pragma unroll
    for (int i = 0; i < 8; ++i)
#pragma unroll
        for (int j = 0; j < 4; ++j) acc[i][j] = zero4;

    const unsigned short* Ab = A + (size_t)mt * 256 * K;
    const unsigned short* Bb = Bt + (size_t)nt * 256 * K;

    // staging: 256x64 tile = 2048 16B-chunks per operand; 4 per thread.
    // LDS dest linear; source column inverse-swizzled (3-bit XOR within 8-chunk row).
    const unsigned short* As[4];
    const unsigned short* Bs[4];
    int ldstA[4], ldstB[4];
#pragma unroll
    for (int j = 0; j < 4; ++j) {
        int ch = tid + j * 512;
        int row = ch >> 3, cpos = ch & 7;
        int scol = ((cpos ^ (row & 7)) << 3);
        As[j] = Ab + (size_t)row * K + scol;
        Bs[j] = Bb + (size_t)row * K + scol;
        ldstA[j] = ch * 16;            // bytes, A at [0,32768)
        ldstB[j] = 32768 + ch * 16;    // B at [32768,65536)
    }

    for (int t = 0; t < 8; ++t) {
        __syncthreads();               // previous step's reads done before overwrite
#pragma unroll
        for (int j = 0; j < 4; ++j) {
            __builtin_amdgcn_global_load_lds(as_gbl(As[j] + t * 64), as_lds(smem + ldstA[j]), 16, 0, 0);
            __builtin_amdgcn_global_load_lds(as_gbl(Bs[j] + t * 64), as_lds(smem + ldstB[j]), 16, 0, 0);
        }
        asm volatile("s_waitcnt vmcnt(0)" ::: "memory");
        __syncthreads();

        const unsigned short* Ar = (const unsigned short*)smem;
        const unsigned short* Br = (const unsigned short*)(smem + 32768);
#pragma unroll
        for (int s = 0; s < 2; ++s) {
            bf16x8 bf[4], af[8];
#pragma unroll
            for (int n = 0; n < 4; ++n)
                bf[n] = ldsrd64(Br, wc * 64 + n * 16 + l15, s * 4 + g);
#pragma unroll
            for (int m = 0; m < 8; ++m)
                af[m] = ldsrd64(Ar, wr * 128 + m * 16 + l15, s * 4 + g);
            __builtin_amdgcn_s_setprio(1);
#pragma unroll
            for (int m = 0; m < 8; ++m)
#pragma unroll
                for (int n = 0; n < 4; ++n)
                    acc[m][n] = __builtin_amdgcn_mfma_f32_16x16x32_bf16(af[m], bf[n], acc[m][n], 0, 0, 0);
            __builtin_amdgcn_s_setprio(0);
        }
    }

    // ---- epilogue: LDS-staged, full-line coalesced f32 stores ----
    __syncthreads();
    const int mrow = mt * 256;
    const int ncol = nt * 256;
    float* Cl = (float*)smem;
    float bvj[4];
#pragma unroll
    for (int j = 0; j < 4; ++j) bvj[j] = bias[ncol + wc * 64 + j * 16 + l15];
    const int srow = tid >> 4;            // 0..31
    const int scol = (tid & 15) * 4;      // 0..60 step 4
    const float* Crd = Cl + srow * 258 + scol;
#pragma unroll
    for (int mc = 0; mc < 8; ++mc) {
        if (wr == (mc >> 2)) {
            int ibase = (mc & 3) * 2;
#pragma unroll
            for (int ii = 0; ii < 2; ++ii) {
                int i = ibase + ii;
                int lr = ii * 16 + g * 4;
#pragma unroll
                for (int j = 0; j < 4; ++j)
#pragma unroll
                    for (int rr = 0; rr < 4; ++rr)
                        Cl[(lr + rr) * 258 + wc * 64 + j * 16 + l15] = acc[i][j][rr] + bvj[j];
            }
        }
        __syncthreads();
        {
            float* gp = Cout + (size_t)(mrow + mc * 32 + srow) * N + ncol + scol;
#pragma unroll
            for (int it = 0; it < 4; ++it)
                *(float4*)(gp + it * 64) = *(const float4*)(Crd + it * 64);
        }
        __syncthreads();
    }
}

extern "C" void kernel_launch(void* const* d_in, const int* in_sizes, int n_in,
                              void* d_out, int out_size, void* d_ws, size_t ws_size,
                              hipStream_t stream)
{
    const int*           ids = (const int*)d_in[0];
    const unsigned char* pad = (const unsigned char*)d_in[1];
    const float*         tbl = (const float*)d_in[2];
    const float*         sfs = (const float*)d_in[3];
    const float*         als = (const float*)d_in[4];
    const float*         fw  = (const float*)d_in[5];
    const float*         fb  = (const float*)d_in[6];
    const float*         ow  = (const float*)d_in[7];
    const float*         ob  = (const float*)d_in[8];
    float* logits = (float*)d_out;

    // d_ws layout (60 MB)
    char* ws = (char*)d_ws;
    unsigned short* outw_bf = (unsigned short*)(ws);              // 32,768,000 B
    unsigned short* fusw_bf = (unsigned short*)(ws + 32768000);   //  2,097,152 B
    unsigned short* emb_bf  = (unsigned short*)(ws + 34865152);   //  4,194,304 B
    unsigned short* concat  = (unsigned short*)(ws + 39059456);   // 16,777,216 B
    unsigned short* fused   = (unsigned short*)(ws + 55836672);   //  4,194,304 B

    // scratch inside d_out (dead until final GEMM overwrites it)
    char* ob_scratch = (char*)d_out;
    unsigned short* P    = (unsigned short*)(ob_scratch);              // 67,108,864 B
    unsigned short* embT = (unsigned short*)(ob_scratch + 67108864);   //  4,194,304 B
    float*          dtab = (float*)(ob_scratch + 71303168);            //     32,768 B
    float*          lsum = (float*)(ob_scratch + 71335936);            //     65,536 B

    k_prep<<<6960, 256, 0, stream>>>(ids, tbl, als, fw, ow,
                                     outw_bf, fusw_bf, emb_bf, embT, dtab, lsum);

    dim3 bg(32, 32, BB);
    k_base<<<bg, 256, 0, stream>>>(emb_bf, pad, sfs, dtab, P, lsum);

    dim3 pg(64, BB, HH);
    k_pv<<<pg, 256, 0, stream>>>(P, embT, lsum, concat);

    k_gemm_bt<0><<<32 * 4, 256, 0, stream>>>(concat, fusw_bf, fb, fused, BB * SB, DD, HH * DD);
    k_logits<<<16 * 125, 512, 0, stream>>>(fused, outw_bf, ob, logits, BB * SB, VV, DD);
}

// Round 12
// 388.983 us; speedup vs baseline: 1.0787x; 1.0787x over previous
//
#include <hip/hip_runtime.h>
#include <hip/hip_bf16.h>
#include <stdint.h>

#define BB 2
#define SB 2048
#define DD 512
#define HH 4
#define VV 32000

typedef __attribute__((ext_vector_type(4))) float f32x4;
typedef __attribute__((ext_vector_type(8))) short bf16x8;
typedef __attribute__((ext_vector_type(4))) unsigned short us4;

__device__ __forceinline__ unsigned short f2bf(float f) {
    unsigned u = __float_as_uint(f);
    u += 0x7fffu + ((u >> 16) & 1u);
    return (unsigned short)(u >> 16);
}

__device__ __forceinline__ __attribute__((address_space(3))) unsigned int*
as_lds(void* p) {
    return (__attribute__((address_space(3))) unsigned int*)(unsigned)(uintptr_t)p;
}
__device__ __forceinline__ const __attribute__((address_space(1))) unsigned int*
as_gbl(const void* p) {
    return (const __attribute__((address_space(1))) unsigned int*)(uintptr_t)p;
}

// ---------------- merged prep kernel ----------------
__global__ void k_prep(const int* __restrict__ ids, const float* __restrict__ tbl,
                       const float* __restrict__ als,
                       const float* __restrict__ fw, const float* __restrict__ ow,
                       unsigned short* __restrict__ outw_bf, unsigned short* __restrict__ fusw_bf,
                       unsigned short* __restrict__ emb, unsigned short* __restrict__ embT,
                       float* __restrict__ dtab, float* __restrict__ lsum)
{
    __shared__ unsigned short TT[64][72];
    const int bid = blockIdx.x, t = threadIdx.x;

    if (bid < 2000) {
        int base = bid * 8192 + t * 4;
#pragma unroll
        for (int it = 0; it < 8; ++it) {
            int i = base + it * 1024;
            float4 v = *(const float4*)(ow + i);
            us4 o; o.x = f2bf(v.x); o.y = f2bf(v.y); o.z = f2bf(v.z); o.w = f2bf(v.w);
            *(us4*)(outw_bf + i) = o;
        }
    } else if (bid < 2256) {
        int base = (bid - 2000) * 4096 + t * 4;
#pragma unroll
        for (int it = 0; it < 4; ++it) {
            int i = base + it * 1024;
            float4 v = *(const float4*)(fw + i);
            us4 o; o.x = f2bf(v.x); o.y = f2bf(v.y); o.z = f2bf(v.z); o.w = f2bf(v.w);
            *(us4*)(fusw_bf + i) = o;
        }
    } else if (bid < 6352) {
        int row = bid - 2256;
        int id = ids[row];
        if (id < 0) id = 0;
        if (id >= VV) id = VV - 1;
        const float* s = tbl + (size_t)id * DD;
        unsigned short* d = emb + (size_t)row * DD;
        d[t]       = f2bf(s[t]);
        d[t + 256] = f2bf(s[t + 256]);
    } else if (bid < 6448) {
        int i = (bid - 6352) * 256 + t;
        if (i < HH * SB) {
            int h = i >> 11, dd = i & (SB - 1);
            dtab[i] = 0.04419417382415922f / (1.f + als[h] * (float)dd);
        } else {
            lsum[i - HH * SB] = 0.f;
        }
    } else {
        int bid2 = bid - 6448;
        const int d0 = (bid2 & 7) * 64, s0 = ((bid2 >> 3) & 31) * 64, b = bid2 >> 8;
        {
            int s = t >> 2, c16 = (t & 3) * 16;
            int id = ids[b * SB + s0 + s];
            if (id < 0) id = 0;
            if (id >= VV) id = VV - 1;
            const float* src = tbl + (size_t)id * DD + d0 + c16;
#pragma unroll
            for (int q4 = 0; q4 < 4; ++q4) {
                float4 v = *(const float4*)(src + q4 * 4);
                TT[c16 + q4 * 4 + 0][s] = f2bf(v.x);
                TT[c16 + q4 * 4 + 1][s] = f2bf(v.y);
                TT[c16 + q4 * 4 + 2][s] = f2bf(v.z);
                TT[c16 + q4 * 4 + 3][s] = f2bf(v.w);
            }
        }
        __syncthreads();
        {
            int d = t >> 2, sc = (t & 3) * 16;
            bf16x8 o0, o1;
#pragma unroll
            for (int j = 0; j < 8; ++j) {
                o0[j] = (short)TT[d][sc + j];
                o1[j] = (short)TT[d][sc + 8 + j];
            }
            unsigned short* dst = embT + ((size_t)(b * DD + d0 + d)) * SB + s0 + sc;
            *(bf16x8*)dst = o0;
            *(bf16x8*)(dst + 8) = o1;
        }
    }
}

// ---------------- phase 2: shared base QK^T -> per-head P tiles + row sums ----------------
__launch_bounds__(256, 2)
__global__ void k_base(const unsigned short* __restrict__ emb,
                       const unsigned char* __restrict__ pad,
                       const float* __restrict__ sfs,
                       const float* __restrict__ dtab,
                       unsigned short* __restrict__ P,      // [4][2][2048][2048]
                       float* __restrict__ lsum)            // [4][2][2048]
{
    const int kt = blockIdx.x, qt = blockIdx.y, b = blockIdx.z;
    if (kt > qt + 1) return;
    const int tid = threadIdx.x, lane = tid & 63, wv = tid >> 6;
    const int l15 = lane & 15, g = lane >> 4;

    if (kt == qt + 1) {
        int row = tid >> 2, cb = (tid & 3) * 16;
        int4 z = {0, 0, 0, 0};
#pragma unroll
        for (int h = 0; h < 4; ++h) {
            unsigned short* Ph = P + (((size_t)(h * 2 + b)) * SB + qt * 64 + row) * SB + kt * 64 + cb;
            *(int4*)Ph = z;
            *(int4*)(Ph + 8) = z;
        }
        return;
    }

    __shared__ __align__(16) unsigned short Ql[64 * 128];
    __shared__ __align__(16) unsigned short Kl[64 * 128];

    const int q = qt * 64 + wv * 16 + l15;

    f32x4 zero4 = {0.f, 0.f, 0.f, 0.f};
    f32x4 cc[4];
#pragma unroll
    for (int c = 0; c < 4; ++c) cc[c] = zero4;

    for (int dc = 0; dc < 4; ++dc) {
        const int d0 = dc * 128;
        __syncthreads();
#pragma unroll
        for (int i = 0; i < 4; ++i) {
            int flat = (i * 256 + tid) * 8;
            int row = flat >> 7;
            int ch  = (flat >> 3) & 15;
            int scol = ((ch ^ (row & 15)) << 3);
            __builtin_amdgcn_global_load_lds(
                as_gbl(emb + ((size_t)(b * SB + qt * 64 + row)) * DD + d0 + scol),
                as_lds(Ql + flat), 16, 0, 0);
            __builtin_amdgcn_global_load_lds(
                as_gbl(emb + ((size_t)(b * SB + kt * 64 + row)) * DD + d0 + scol),
                as_lds(Kl + flat), 16, 0, 0);
        }
        asm volatile("s_waitcnt vmcnt(0)" ::: "memory");
        __syncthreads();

#pragma unroll
        for (int dsl = 0; dsl < 4; ++dsl) {
            int chr = (dsl * 4 + g);
            bf16x8 qf = *(const bf16x8*)(Ql + (wv * 16 + l15) * 128 + ((chr ^ l15) << 3));
#pragma unroll
            for (int c = 0; c < 4; ++c) {
                bf16x8 kf = *(const bf16x8*)(Kl + (c * 16 + l15) * 128 + ((chr ^ l15) << 3));
                cc[c] = __builtin_amdgcn_mfma_f32_16x16x32_bf16(kf, qf, cc[c], 0, 0, 0);
            }
        }
    }

    unsigned long long padm = __ballot(pad[(size_t)b * SB + kt * 64 + lane] != 0);

    const int wins[4] = {1 << 30, 128, 512, 1 << 30};
#pragma unroll
    for (int h = 0; h < 4; ++h) {
        const int win = wins[h];
        if (kt * 64 + win + 192 < qt * 64) continue;
        const float sf = sfs[h];
        const float* dth = dtab + h * SB;
        float rsum = 0.f;
        unsigned short pb[4][4];
#pragma unroll
        for (int c = 0; c < 4; ++c) {
#pragma unroll
            for (int r = 0; r < 4; ++r) {
                int kk = kt * 64 + c * 16 + 4 * g + r;
                int dist = q - kk;
                float p = 0.f;
                if (dist >= 0 && dist <= win &&
                    ((dist == 0) || !((padm >> (c * 16 + 4 * g + r)) & 1ull))) {
                    float s = cc[c][r] * dth[dist];
                    if (dist == 0) s *= sf;
                    p = __expf(s);
                }
                rsum += p;
                pb[c][r] = f2bf(p);
            }
        }
        unsigned short* Ph = P + (((size_t)(h * 2 + b)) * SB + q) * SB + kt * 64;
#pragma unroll
        for (int c = 0; c < 4; ++c) {
            us4 o;
            o.x = pb[c][0]; o.y = pb[c][1]; o.z = pb[c][2]; o.w = pb[c][3];
            *(us4*)(Ph + c * 16 + 4 * g) = o;
        }
        rsum += __shfl_xor(rsum, 16, 64);
        rsum += __shfl_xor(rsum, 32, 64);
        if (lane < 16)
            atomicAdd(&lsum[((size_t)(h * 2 + b)) * SB + q], rsum);
    }
}

// ---------------- phase 3: ctx = P * V^T, normalize, write concat ----------------
__launch_bounds__(256, 2)
__global__ void k_pv(const unsigned short* __restrict__ P,
                     const unsigned short* __restrict__ embT,
                     const float* __restrict__ lsum,
                     unsigned short* __restrict__ concat)
{
    const int t64 = blockIdx.x, b = blockIdx.y, h = blockIdx.z;
    const int mt = t64 >> 2, nt = t64 & 3;
    const int Q0 = mt * 128;
    const int win = (h == 1) ? 128 : (h == 2) ? 512 : (1 << 30);
    int klo = Q0 - win - 64; if (klo < 0) klo = 0; klo &= ~63;
    const int khi = Q0 + 128;

    __shared__ __align__(16) unsigned short Al[128 * 32];
    __shared__ __align__(16) unsigned short Bl[128 * 32];

    const int tid = threadIdx.x, lane = tid & 63, wv = tid >> 6;
    const int wm = (wv >> 1) * 64, wn = (wv & 1) * 64;
    const int l15 = lane & 15, g = lane >> 4;

    f32x4 zero4 = {0.f, 0.f, 0.f, 0.f};
    f32x4 acc[4][4];
#pragma unroll
    for (int i = 0; i < 4; ++i)
#pragma unroll
        for (int j = 0; j < 4; ++j) acc[i][j] = zero4;

    const unsigned short* Ab = P + (((size_t)(h * 2 + b)) * SB + Q0) * SB;
    const unsigned short* Bb = embT + ((size_t)(b * DD + nt * 128)) * SB;

    for (int k0 = klo; k0 < khi; k0 += 32) {
        __syncthreads();
#pragma unroll
        for (int s = 0; s < 2; ++s) {
            int e = (s * 256 + tid) * 8;
            int row = e >> 5, col = e & 31;
            __builtin_amdgcn_global_load_lds(as_gbl(Ab + (size_t)row * SB + k0 + col),
                                             as_lds(Al + e), 16, 0, 0);
            __builtin_amdgcn_global_load_lds(as_gbl(Bb + (size_t)row * SB + k0 + col),
                                             as_lds(Bl + e), 16, 0, 0);
        }
        asm volatile("s_waitcnt vmcnt(0)" ::: "memory");
        __syncthreads();

        bf16x8 af[4], bfr[4];
#pragma unroll
        for (int i = 0; i < 4; ++i) {
            af[i]  = *(const bf16x8*)(Al + (wm + i * 16 + l15) * 32 + 8 * g);
            bfr[i] = *(const bf16x8*)(Bl + (wn + i * 16 + l15) * 32 + 8 * g);
        }
#pragma unroll
        for (int i = 0; i < 4; ++i)
#pragma unroll
            for (int j = 0; j < 4; ++j)
                acc[i][j] = __builtin_amdgcn_mfma_f32_16x16x32_bf16(af[i], bfr[j], acc[i][j], 0, 0, 0);
    }

    const float* ls = lsum + ((size_t)(h * 2 + b)) * SB;
    unsigned short* cb = concat + ((size_t)(b * SB)) * (HH * DD) + h * DD + nt * 128;
#pragma unroll
    for (int i = 0; i < 4; ++i) {
        int rowb = wm + i * 16 + g * 4;
        float inv[4];
#pragma unroll
        for (int rr = 0; rr < 4; ++rr) inv[rr] = 1.f / ls[Q0 + rowb + rr];
#pragma unroll
        for (int j = 0; j < 4; ++j) {
            int col = wn + j * 16 + l15;
#pragma unroll
            for (int rr = 0; rr < 4; ++rr)
                cb[(size_t)(Q0 + rowb + rr) * (HH * DD) + col] = f2bf(acc[i][j][rr] * inv[rr]);
        }
    }
}

// ---------------- m97-style 128x128 GEMM (fusion GEMM) ----------------
template <int OUTF32>
__launch_bounds__(256, 2)
__global__ void k_gemm_bt(const unsigned short* __restrict__ A,
                          const unsigned short* __restrict__ Bt,
                          const float* __restrict__ bias,
                          void* __restrict__ Cout,
                          int M, int N, int K)
{
    const int nMt = M >> 7;
    const int nwg = gridDim.x;
    int bid = blockIdx.x;
    int q = nwg >> 3, r = nwg & 7;
    int x = bid & 7, o = bid >> 3;
    int wg = (x < r ? x * (q + 1) : r * (q + 1) + (x - r) * q) + o;
    const int mt = wg % nMt, nt = wg / nMt;

    __shared__ __align__(16) unsigned short Al[128 * 32];
    __shared__ __align__(16) unsigned short Bl[128 * 32];

    const int tid = threadIdx.x;
    const int lane = tid & 63;
    const int wv = tid >> 6;
    const int wm = (wv >> 1) * 64, wn = (wv & 1) * 64;
    const int l15 = lane & 15, g = lane >> 4;

    f32x4 zero4 = {0.f, 0.f, 0.f, 0.f};
    f32x4 acc[4][4];
#pragma unroll
    for (int i = 0; i < 4; ++i)
#pragma unroll
        for (int j = 0; j < 4; ++j) acc[i][j] = zero4;

    const unsigned short* Ab = A + (size_t)mt * 128 * K;
    const unsigned short* Bb = Bt + (size_t)nt * 128 * K;

    for (int k0 = 0; k0 < K; k0 += 32) {
        __syncthreads();
#pragma unroll
        for (int s = 0; s < 2; ++s) {
            int e = (s * 256 + tid) * 8;
            int row = e >> 5, col = e & 31;
            __builtin_amdgcn_global_load_lds(as_gbl(Ab + (size_t)row * K + k0 + col),
                                             as_lds(Al + e), 16, 0, 0);
            __builtin_amdgcn_global_load_lds(as_gbl(Bb + (size_t)row * K + k0 + col),
                                             as_lds(Bl + e), 16, 0, 0);
        }
        asm volatile("s_waitcnt vmcnt(0)" ::: "memory");
        __syncthreads();

        bf16x8 af[4], bfr[4];
#pragma unroll
        for (int i = 0; i < 4; ++i) {
            af[i]  = *(const bf16x8*)(Al + (wm + i * 16 + l15) * 32 + 8 * g);
            bfr[i] = *(const bf16x8*)(Bl + (wn + i * 16 + l15) * 32 + 8 * g);
        }
#pragma unroll
        for (int i = 0; i < 4; ++i)
#pragma unroll
            for (int j = 0; j < 4; ++j)
                acc[i][j] = __builtin_amdgcn_mfma_f32_16x16x32_bf16(af[i], bfr[j], acc[i][j], 0, 0, 0);
    }

#pragma unroll
    for (int i = 0; i < 4; ++i) {
        int rowb = mt * 128 + wm + i * 16 + g * 4;
#pragma unroll
        for (int j = 0; j < 4; ++j) {
            int col = nt * 128 + wn + j * 16 + l15;
            float bv = bias[col];
            if (OUTF32) {
                float* C = (float*)Cout;
#pragma unroll
                for (int rr = 0; rr < 4; ++rr)
                    C[(size_t)(rowb + rr) * N + col] = acc[i][j][rr] + bv;
            } else {
                unsigned short* C = (unsigned short*)Cout;
#pragma unroll
                for (int rr = 0; rr < 4; ++rr)
                    C[(size_t)(rowb + rr) * N + col] = f2bf(acc[i][j][rr] + bv);
            }
        }
    }
}

// ---------------- logits GEMM v8: 512x128 tile, BK=32 dbuf, 80KB LDS, 2 blk/CU ----------
// Traffic-optimized: B re-read x8 (256 MB, was 512); A L2-resident via XCD chunking.
// 512 thr = 8 waves (wr 4 x wc 2, per-wave 128x64). dbuf schedule identical to R5-best.
__launch_bounds__(512, 2)
__global__ void k_logits(const unsigned short* __restrict__ A,
                         const unsigned short* __restrict__ Bt,
                         const float* __restrict__ bias,
                         float* __restrict__ Cout,
                         int M, int N, int K)
{
    const int nMt = M >> 9;               // 8
    const int nwg = gridDim.x;            // 2000
    int bid = blockIdx.x;
    int q = nwg >> 3, r = nwg & 7;
    int x = bid & 7, o = bid >> 3;
    int wg = (x < r ? x * (q + 1) : r * (q + 1) + (x - r) * q) + o;
    const int mt = wg % nMt, nt = wg / nMt;   // mt-fastest: XCD slab shares all of A

    // LDS: A0 [0,32K) A1 [32K,64K) B0 [64K,72K) B1 [72K,80K)
    __shared__ __align__(16) char smem[81920];

    const int tid = threadIdx.x, lane = tid & 63, wv = tid >> 6;
    const int wr = wv >> 1, wc = wv & 1;
    const int l15 = lane & 15, g = lane >> 4;

    f32x4 zero4 = {0.f, 0.f, 0.f, 0.f};
    f32x4 acc[8][4];
#pragma unroll
    for (int i = 0; i < 8; ++i)
#pragma unroll
        for (int j = 0; j < 4; ++j) acc[i][j] = zero4;

    const unsigned short* Ab = A + (size_t)mt * 512 * K;
    const unsigned short* Bb = Bt + (size_t)nt * 128 * K;

    // staging: A = 512x32 = 2048 chunks16 (4/thr); B = 128x32 = 512 chunks16 (1/thr).
    // LDS dest linear; source col inverse-swizzled (2-bit XOR within 4-chunk row).
    const unsigned short* As[4];
    int ldstA[4];
#pragma unroll
    for (int j = 0; j < 4; ++j) {
        int ch = tid + j * 512;
        int row = ch >> 2, p = ch & 3;
        int scol = ((p ^ (row & 3)) << 3);
        As[j] = Ab + (size_t)row * K + scol;
        ldstA[j] = ch * 16;
    }
    const unsigned short* Bsrc;
    int ldstB;
    {
        int row = tid >> 2, p = tid & 3;
        int scol = ((p ^ (row & 3)) << 3);
        Bsrc = Bb + (size_t)row * K + scol;
        ldstB = 65536 + tid * 16;
    }

#define STG(bufi_, k0_) {                                                                   \
    _Pragma("unroll")                                                                       \
    for (int j = 0; j < 4; ++j)                                                             \
        __builtin_amdgcn_global_load_lds(as_gbl(As[j] + (k0_)),                             \
            as_lds(smem + (bufi_) * 32768 + ldstA[j]), 16, 0, 0);                           \
    __builtin_amdgcn_global_load_lds(as_gbl(Bsrc + (k0_)),                                  \
        as_lds(smem + (bufi_) * 8192 + ldstB), 16, 0, 0); }

    STG(0, 0);
    __syncthreads();

    for (int t = 0; t < 16; ++t) {
        const int cur = t & 1;
        if (t < 15) STG(cur ^ 1, (t + 1) * 32);
        const unsigned short* Ar = (const unsigned short*)(smem + cur * 32768);
        const unsigned short* Br = (const unsigned short*)(smem + 65536 + cur * 8192);

        bf16x8 bf[4], af[8];
#pragma unroll
        for (int n = 0; n < 4; ++n) {
            int row = wc * 64 + n * 16 + l15;
            bf[n] = *(const bf16x8*)((const char*)Br + row * 64 + ((g ^ (row & 3)) << 4));
        }
#pragma unroll
        for (int m = 0; m < 8; ++m) {
            int row = wr * 128 + m * 16 + l15;
            af[m] = *(const bf16x8*)((const char*)Ar + row * 64 + ((g ^ (row & 3)) << 4));
        }
        __builtin_amdgcn_s_setprio(1);
#pragma unroll
        for (int m = 0; m < 8; ++m)
#pragma unroll
            for (int n = 0; n < 4; ++n)
                acc[m][n] = __builtin_amdgcn_mfma_f32_16x16x32_bf16(af[m], bf[n], acc[m][n], 0, 0, 0);
        __builtin_amdgcn_s_setprio(0);
        __syncthreads();    // stage(t+1) landed; reads of buf cur done
    }
#undef STG

    // ---- epilogue: direct f32 stores (proven ~neutral vs LDS-staged) ----
    const int mrow = mt * 512 + wr * 128;
    const int ncol = nt * 128 + wc * 64;
#pragma unroll
    for (int i = 0; i < 8; ++i) {
        int rowb = mrow + i * 16 + g * 4;
#pragma unroll
        for (int j = 0; j < 4; ++j) {
            int col = ncol + j * 16 + l15;
            float bv = bias[col];
#pragma unroll
            for (int rr = 0; rr < 4; ++rr)
                Cout[(size_t)(rowb + rr) * N + col] = acc[i][j][rr] + bv;
        }
    }
}

extern "C" void kernel_launch(void* const* d_in, const int* in_sizes, int n_in,
                              void* d_out, int out_size, void* d_ws, size_t ws_size,
                              hipStream_t stream)
{
    const int*           ids = (const int*)d_in[0];
    const unsigned char* pad = (const unsigned char*)d_in[1];
    const float*         tbl = (const float*)d_in[2];
    const float*         sfs = (const float*)d_in[3];
    const float*         als = (const float*)d_in[4];
    const float*         fw  = (const float*)d_in[5];
    const float*         fb  = (const float*)d_in[6];
    const float*         ow  = (const float*)d_in[7];
    const float*         ob  = (const float*)d_in[8];
    float* logits = (float*)d_out;

    // d_ws layout (60 MB)
    char* ws = (char*)d_ws;
    unsigned short* outw_bf = (unsigned short*)(ws);              // 32,768,000 B
    unsigned short* fusw_bf = (unsigned short*)(ws + 32768000);   //  2,097,152 B
    unsigned short* emb_bf  = (unsigned short*)(ws + 34865152);   //  4,194,304 B
    unsigned short* concat  = (unsigned short*)(ws + 39059456);   // 16,777,216 B
    unsigned short* fused   = (unsigned short*)(ws + 55836672);   //  4,194,304 B

    // scratch inside d_out (dead until final GEMM overwrites it)
    char* ob_scratch = (char*)d_out;
    unsigned short* P    = (unsigned short*)(ob_scratch);              // 67,108,864 B
    unsigned short* embT = (unsigned short*)(ob_scratch + 67108864);   //  4,194,304 B
    float*          dtab = (float*)(ob_scratch + 71303168);            //     32,768 B
    float*          lsum = (float*)(ob_scratch + 71335936);            //     65,536 B

    k_prep<<<6960, 256, 0, stream>>>(ids, tbl, als, fw, ow,
                                     outw_bf, fusw_bf, emb_bf, embT, dtab, lsum);

    dim3 bg(32, 32, BB);
    k_base<<<bg, 256, 0, stream>>>(emb_bf, pad, sfs, dtab, P, lsum);

    dim3 pg(64, BB, HH);
    k_pv<<<pg, 256, 0, stream>>>(P, embT, lsum, concat);

    k_gemm_bt<0><<<32 * 4, 256, 0, stream>>>(concat, fusw_bf, fb, fused, BB * SB, DD, HH * DD);
    k_logits<<<8 * 250, 512, 0, stream>>>(fused, outw_bf, ob, logits, BB * SB, VV, DD);
}

// Round 13
// 367.595 us; speedup vs baseline: 1.1415x; 1.0582x over previous
//
#include <hip/hip_runtime.h>
#include <hip/hip_bf16.h>
#include <stdint.h>

#define BB 2
#define SB 2048
#define DD 512
#define HH 4
#define VV 32000

typedef __attribute__((ext_vector_type(4))) float f32x4;
typedef __attribute__((ext_vector_type(8))) short bf16x8;
typedef __attribute__((ext_vector_type(4))) unsigned short us4;

__device__ __forceinline__ unsigned short f2bf(float f) {
    unsigned u = __float_as_uint(f);
    u += 0x7fffu + ((u >> 16) & 1u);
    return (unsigned short)(u >> 16);
}

__device__ __forceinline__ __attribute__((address_space(3))) unsigned int*
as_lds(void* p) {
    return (__attribute__((address_space(3))) unsigned int*)(unsigned)(uintptr_t)p;
}
__device__ __forceinline__ const __attribute__((address_space(1))) unsigned int*
as_gbl(const void* p) {
    return (const __attribute__((address_space(1))) unsigned int*)(uintptr_t)p;
}

// swizzled read from a [rows][64] bf16 LDS tile (128B rows): logical 16B-chunk c
// lives at slot c^(row&7). 2-way residual conflict (free).
__device__ __forceinline__ bf16x8 ldsrd64(const unsigned short* base, int row, int c) {
    return *(const bf16x8*)((const char*)base + row * 128 + ((c ^ (row & 7)) << 4));
}

// ---------------- merged prep kernel ----------------
__global__ void k_prep(const int* __restrict__ ids, const float* __restrict__ tbl,
                       const float* __restrict__ als,
                       const float* __restrict__ fw, const float* __restrict__ ow,
                       unsigned short* __restrict__ outw_bf, unsigned short* __restrict__ fusw_bf,
                       unsigned short* __restrict__ emb, unsigned short* __restrict__ embT,
                       float* __restrict__ dtab, float* __restrict__ lsum)
{
    __shared__ unsigned short TT[64][72];
    const int bid = blockIdx.x, t = threadIdx.x;

    if (bid < 2000) {
        int base = bid * 8192 + t * 4;
#pragma unroll
        for (int it = 0; it < 8; ++it) {
            int i = base + it * 1024;
            float4 v = *(const float4*)(ow + i);
            us4 o; o.x = f2bf(v.x); o.y = f2bf(v.y); o.z = f2bf(v.z); o.w = f2bf(v.w);
            *(us4*)(outw_bf + i) = o;
        }
    } else if (bid < 2256) {
        int base = (bid - 2000) * 4096 + t * 4;
#pragma unroll
        for (int it = 0; it < 4; ++it) {
            int i = base + it * 1024;
            float4 v = *(const float4*)(fw + i);
            us4 o; o.x = f2bf(v.x); o.y = f2bf(v.y); o.z = f2bf(v.z); o.w = f2bf(v.w);
            *(us4*)(fusw_bf + i) = o;
        }
    } else if (bid < 6352) {
        int row = bid - 2256;
        int id = ids[row];
        if (id < 0) id = 0;
        if (id >= VV) id = VV - 1;
        const float* s = tbl + (size_t)id * DD;
        unsigned short* d = emb + (size_t)row * DD;
        d[t]       = f2bf(s[t]);
        d[t + 256] = f2bf(s[t + 256]);
    } else if (bid < 6448) {
        int i = (bid - 6352) * 256 + t;
        if (i < HH * SB) {
            int h = i >> 11, dd = i & (SB - 1);
            dtab[i] = 0.04419417382415922f / (1.f + als[h] * (float)dd);
        } else {
            lsum[i - HH * SB] = 0.f;
        }
    } else {
        int bid2 = bid - 6448;
        const int d0 = (bid2 & 7) * 64, s0 = ((bid2 >> 3) & 31) * 64, b = bid2 >> 8;
        {
            int s = t >> 2, c16 = (t & 3) * 16;
            int id = ids[b * SB + s0 + s];
            if (id < 0) id = 0;
            if (id >= VV) id = VV - 1;
            const float* src = tbl + (size_t)id * DD + d0 + c16;
#pragma unroll
            for (int q4 = 0; q4 < 4; ++q4) {
                float4 v = *(const float4*)(src + q4 * 4);
                TT[c16 + q4 * 4 + 0][s] = f2bf(v.x);
                TT[c16 + q4 * 4 + 1][s] = f2bf(v.y);
                TT[c16 + q4 * 4 + 2][s] = f2bf(v.z);
                TT[c16 + q4 * 4 + 3][s] = f2bf(v.w);
            }
        }
        __syncthreads();
        {
            int d = t >> 2, sc = (t & 3) * 16;
            bf16x8 o0, o1;
#pragma unroll
            for (int j = 0; j < 8; ++j) {
                o0[j] = (short)TT[d][sc + j];
                o1[j] = (short)TT[d][sc + 8 + j];
            }
            unsigned short* dst = embT + ((size_t)(b * DD + d0 + d)) * SB + s0 + sc;
            *(bf16x8*)dst = o0;
            *(bf16x8*)(dst + 8) = o1;
        }
    }
}

// ---------------- phase 2: shared base QK^T, dc-double-buffered ----------------
__launch_bounds__(256, 2)
__global__ void k_base(const unsigned short* __restrict__ emb,
                       const unsigned char* __restrict__ pad,
                       const float* __restrict__ sfs,
                       const float* __restrict__ dtab,
                       unsigned short* __restrict__ P,      // [4][2][2048][2048]
                       float* __restrict__ lsum)            // [4][2][2048]
{
    const int kt = blockIdx.x, qt = blockIdx.y, b = blockIdx.z;
    if (kt > qt + 1) return;
    const int tid = threadIdx.x, lane = tid & 63, wv = tid >> 6;
    const int l15 = lane & 15, g = lane >> 4;

    if (kt == qt + 1) {
        int row = tid >> 2, cb = (tid & 3) * 16;
        int4 z = {0, 0, 0, 0};
#pragma unroll
        for (int h = 0; h < 4; ++h) {
            unsigned short* Ph = P + (((size_t)(h * 2 + b)) * SB + qt * 64 + row) * SB + kt * 64 + cb;
            *(int4*)Ph = z;
            *(int4*)(Ph + 8) = z;
        }
        return;
    }

    __shared__ __align__(16) unsigned short Ql[2][64 * 128];
    __shared__ __align__(16) unsigned short Kl[2][64 * 128];

    const int q = qt * 64 + wv * 16 + l15;

#define STAGEB(buf_, dc_) {                                                            \
    _Pragma("unroll")                                                                  \
    for (int i = 0; i < 4; ++i) {                                                      \
        int flat = (i * 256 + tid) * 8;                                                \
        int row = flat >> 7;                                                           \
        int ch  = (flat >> 3) & 15;                                                    \
        int scol = ((ch ^ (row & 15)) << 3);                                           \
        __builtin_amdgcn_global_load_lds(                                              \
            as_gbl(emb + ((size_t)(b * SB + qt * 64 + row)) * DD + (dc_) * 128 + scol),\
            as_lds(Ql[buf_] + flat), 16, 0, 0);                                        \
        __builtin_amdgcn_global_load_lds(                                              \
            as_gbl(emb + ((size_t)(b * SB + kt * 64 + row)) * DD + (dc_) * 128 + scol),\
            as_lds(Kl[buf_] + flat), 16, 0, 0);                                        \
    } }

    f32x4 zero4 = {0.f, 0.f, 0.f, 0.f};
    f32x4 cc[4];
#pragma unroll
    for (int c = 0; c < 4; ++c) cc[c] = zero4;

    STAGEB(0, 0);
    __syncthreads();
    for (int dc = 0; dc < 4; ++dc) {
        const int cur = dc & 1;
        if (dc < 3) STAGEB(cur ^ 1, dc + 1);
#pragma unroll
        for (int dsl = 0; dsl < 4; ++dsl) {
            int chr = (dsl * 4 + g);
            bf16x8 qf = *(const bf16x8*)(Ql[cur] + (wv * 16 + l15) * 128 + ((chr ^ l15) << 3));
#pragma unroll
            for (int c = 0; c < 4; ++c) {
                bf16x8 kf = *(const bf16x8*)(Kl[cur] + (c * 16 + l15) * 128 + ((chr ^ l15) << 3));
                cc[c] = __builtin_amdgcn_mfma_f32_16x16x32_bf16(kf, qf, cc[c], 0, 0, 0);
            }
        }
        __syncthreads();
    }
#undef STAGEB

    unsigned long long padm = __ballot(pad[(size_t)b * SB + kt * 64 + lane] != 0);

    const int wins[4] = {1 << 30, 128, 512, 1 << 30};
#pragma unroll
    for (int h = 0; h < 4; ++h) {
        const int win = wins[h];
        if (kt * 64 + win + 192 < qt * 64) continue;
        const float sf = sfs[h];
        const float* dth = dtab + h * SB;
        float rsum = 0.f;
        unsigned short pb[4][4];
#pragma unroll
        for (int c = 0; c < 4; ++c) {
#pragma unroll
            for (int r = 0; r < 4; ++r) {
                int kk = kt * 64 + c * 16 + 4 * g + r;
                int dist = q - kk;
                float p = 0.f;
                if (dist >= 0 && dist <= win &&
                    ((dist == 0) || !((padm >> (c * 16 + 4 * g + r)) & 1ull))) {
                    float s = cc[c][r] * dth[dist];
                    if (dist == 0) s *= sf;
                    p = __expf(s);
                }
                rsum += p;
                pb[c][r] = f2bf(p);
            }
        }
        unsigned short* Ph = P + (((size_t)(h * 2 + b)) * SB + q) * SB + kt * 64;
#pragma unroll
        for (int c = 0; c < 4; ++c) {
            us4 o;
            o.x = pb[c][0]; o.y = pb[c][1]; o.z = pb[c][2]; o.w = pb[c][3];
            *(us4*)(Ph + c * 16 + 4 * g) = o;
        }
        rsum += __shfl_xor(rsum, 16, 64);
        rsum += __shfl_xor(rsum, 32, 64);
        if (lane < 16)
            atomicAdd(&lsum[((size_t)(h * 2 + b)) * SB + q], rsum);
    }
}

// ---------------- phase 3: ctx = P * V^T, BK=64 double-buffered ----------------
__launch_bounds__(256, 2)
__global__ void k_pv(const unsigned short* __restrict__ P,
                     const unsigned short* __restrict__ embT,
                     const float* __restrict__ lsum,
                     unsigned short* __restrict__ concat)
{
    const int t64 = blockIdx.x, b = blockIdx.y, h = blockIdx.z;
    const int mt = t64 >> 2, nt = t64 & 3;
    const int Q0 = mt * 128;
    const int win = (h == 1) ? 128 : (h == 2) ? 512 : (1 << 30);
    int klo = Q0 - win - 64; if (klo < 0) klo = 0; klo &= ~63;
    const int khi = Q0 + 128;
    const int nsteps = (khi - klo) >> 6;

    __shared__ __align__(16) unsigned short Pl[2][128 * 64];
    __shared__ __align__(16) unsigned short Vl[2][128 * 64];

    const int tid = threadIdx.x, lane = tid & 63, wv = tid >> 6;
    const int wm = (wv >> 1) * 64, wn = (wv & 1) * 64;
    const int l15 = lane & 15, g = lane >> 4;

    f32x4 zero4 = {0.f, 0.f, 0.f, 0.f};
    f32x4 acc[4][4];
#pragma unroll
    for (int i = 0; i < 4; ++i)
#pragma unroll
        for (int j = 0; j < 4; ++j) acc[i][j] = zero4;

    const unsigned short* Ab = P + (((size_t)(h * 2 + b)) * SB + Q0) * SB;
    const unsigned short* Bb = embT + ((size_t)(b * DD + nt * 128)) * SB;

    // staging geometry: 128x64 tile = 1024 chunks16, 4/thread; inverse-swizzled source col.
    const unsigned short* Ps[4];
    const unsigned short* Vs[4];
    int ldst[4];
#pragma unroll
    for (int j = 0; j < 4; ++j) {
        int ch = j * 256 + tid;
        int row = ch >> 3, cpos = ch & 7;
        int scol = ((cpos ^ (row & 7)) << 3);
        Ps[j] = Ab + (size_t)row * SB + scol;
        Vs[j] = Bb + (size_t)row * SB + scol;
        ldst[j] = ch * 16;
    }

#define STAGEPV(buf_, k0_) {                                                           \
    _Pragma("unroll")                                                                  \
    for (int j = 0; j < 4; ++j) {                                                      \
        __builtin_amdgcn_global_load_lds(as_gbl(Ps[j] + (k0_)),                        \
            as_lds((char*)Pl[buf_] + ldst[j]), 16, 0, 0);                              \
        __builtin_amdgcn_global_load_lds(as_gbl(Vs[j] + (k0_)),                        \
            as_lds((char*)Vl[buf_] + ldst[j]), 16, 0, 0);                              \
    } }

    STAGEPV(0, klo);
    __syncthreads();
    for (int t = 0; t < nsteps; ++t) {
        const int cur = t & 1;
        if (t + 1 < nsteps) STAGEPV(cur ^ 1, klo + (t + 1) * 64);
#pragma unroll
        for (int s = 0; s < 2; ++s) {
            bf16x8 af[4], bfr[4];
#pragma unroll
            for (int i = 0; i < 4; ++i) {
                af[i]  = ldsrd64(Pl[cur], wm + i * 16 + l15, s * 4 + g);
                bfr[i] = ldsrd64(Vl[cur], wn + i * 16 + l15, s * 4 + g);
            }
#pragma unroll
            for (int i = 0; i < 4; ++i)
#pragma unroll
                for (int j = 0; j < 4; ++j)
                    acc[i][j] = __builtin_amdgcn_mfma_f32_16x16x32_bf16(af[i], bfr[j], acc[i][j], 0, 0, 0);
        }
        __syncthreads();
    }
#undef STAGEPV

    const float* ls = lsum + ((size_t)(h * 2 + b)) * SB;
    unsigned short* cb = concat + ((size_t)(b * SB)) * (HH * DD) + h * DD + nt * 128;
#pragma unroll
    for (int i = 0; i < 4; ++i) {
        int rowb = wm + i * 16 + g * 4;
        float inv[4];
#pragma unroll
        for (int rr = 0; rr < 4; ++rr) inv[rr] = 1.f / ls[Q0 + rowb + rr];
#pragma unroll
        for (int j = 0; j < 4; ++j) {
            int col = wn + j * 16 + l15;
#pragma unroll
            for (int rr = 0; rr < 4; ++rr)
                cb[(size_t)(Q0 + rowb + rr) * (HH * DD) + col] = f2bf(acc[i][j][rr] * inv[rr]);
        }
    }
}

// ---------------- fusion GEMM: 128x128, BK=32 double-buffered ----------------
template <int OUTF32>
__launch_bounds__(256, 2)
__global__ void k_gemm_bt(const unsigned short* __restrict__ A,
                          const unsigned short* __restrict__ Bt,
                          const float* __restrict__ bias,
                          void* __restrict__ Cout,
                          int M, int N, int K)
{
    const int nMt = M >> 7;
    const int nwg = gridDim.x;
    int bid = blockIdx.x;
    int q = nwg >> 3, r = nwg & 7;
    int x = bid & 7, o = bid >> 3;
    int wg = (x < r ? x * (q + 1) : r * (q + 1) + (x - r) * q) + o;
    const int mt = wg % nMt, nt = wg / nMt;

    __shared__ __align__(16) unsigned short Al[2][128 * 32];
    __shared__ __align__(16) unsigned short Bl[2][128 * 32];

    const int tid = threadIdx.x;
    const int lane = tid & 63;
    const int wv = tid >> 6;
    const int wm = (wv >> 1) * 64, wn = (wv & 1) * 64;
    const int l15 = lane & 15, g = lane >> 4;

    f32x4 zero4 = {0.f, 0.f, 0.f, 0.f};
    f32x4 acc[4][4];
#pragma unroll
    for (int i = 0; i < 4; ++i)
#pragma unroll
        for (int j = 0; j < 4; ++j) acc[i][j] = zero4;

    const unsigned short* Ab = A + (size_t)mt * 128 * K;
    const unsigned short* Bb = Bt + (size_t)nt * 128 * K;

#define STAGEF(buf_, k0_) {                                                            \
    _Pragma("unroll")                                                                  \
    for (int s = 0; s < 2; ++s) {                                                      \
        int e = (s * 256 + tid) * 8;                                                   \
        int row = e >> 5, col = e & 31;                                                \
        __builtin_amdgcn_global_load_lds(as_gbl(Ab + (size_t)row * K + (k0_) + col),   \
                                         as_lds(Al[buf_] + e), 16, 0, 0);              \
        __builtin_amdgcn_global_load_lds(as_gbl(Bb + (size_t)row * K + (k0_) + col),   \
                                         as_lds(Bl[buf_] + e), 16, 0, 0);              \
    } }

    const int nk = K >> 5;
    STAGEF(0, 0);
    __syncthreads();
    for (int t = 0; t < nk; ++t) {
        const int cur = t & 1;
        if (t + 1 < nk) STAGEF(cur ^ 1, (t + 1) * 32);
        bf16x8 af[4], bfr[4];
#pragma unroll
        for (int i = 0; i < 4; ++i) {
            af[i]  = *(const bf16x8*)(Al[cur] + (wm + i * 16 + l15) * 32 + 8 * g);
            bfr[i] = *(const bf16x8*)(Bl[cur] + (wn + i * 16 + l15) * 32 + 8 * g);
        }
#pragma unroll
        for (int i = 0; i < 4; ++i)
#pragma unroll
            for (int j = 0; j < 4; ++j)
                acc[i][j] = __builtin_amdgcn_mfma_f32_16x16x32_bf16(af[i], bfr[j], acc[i][j], 0, 0, 0);
        __syncthreads();
    }
#undef STAGEF

#pragma unroll
    for (int i = 0; i < 4; ++i) {
        int rowb = mt * 128 + wm + i * 16 + g * 4;
#pragma unroll
        for (int j = 0; j < 4; ++j) {
            int col = nt * 128 + wn + j * 16 + l15;
            float bv = bias[col];
            if (OUTF32) {
                float* C = (float*)Cout;
#pragma unroll
                for (int rr = 0; rr < 4; ++rr)
                    C[(size_t)(rowb + rr) * N + col] = acc[i][j][rr] + bv;
            } else {
                unsigned short* C = (unsigned short*)Cout;
#pragma unroll
                for (int rr = 0; rr < 4; ++rr)
                    C[(size_t)(rowb + rr) * N + col] = f2bf(acc[i][j][rr] + bv);
            }
        }
    }
}

// ---------------- logits GEMM: R7-exact (256x256, BK=64 dbuf, LDS epilogue) ----------
__launch_bounds__(512, 1)
__global__ void k_logits(const unsigned short* __restrict__ A,
                         const unsigned short* __restrict__ Bt,
                         const float* __restrict__ bias,
                         float* __restrict__ Cout,
                         int M, int N, int K)
{
    const int nMt = M >> 8;
    const int nwg = gridDim.x;
    int bid = blockIdx.x;
    int q = nwg >> 3, r = nwg & 7;
    int x = bid & 7, o = bid >> 3;
    int wg = (x < r ? x * (q + 1) : r * (q + 1) + (x - r) * q) + o;
    const int mt = wg % nMt, nt = wg / nMt;

    __shared__ __align__(16) char smem[131072];

    const int tid = threadIdx.x, lane = tid & 63, wv = tid >> 6;
    const int wr = wv >> 2, wc = wv & 3;
    const int l15 = lane & 15, g = lane >> 4;

    f32x4 zero4 = {0.f, 0.f, 0.f, 0.f};
    f32x4 acc[8][4];
#pragma unroll
    for (int i = 0; i < 8; ++i)
#pragma unroll
        for (int j = 0; j < 4; ++j) acc[i][j] = zero4;

    const unsigned short* Ab = A + (size_t)mt * 256 * K;
    const unsigned short* Bb = Bt + (size_t)nt * 256 * K;

    const unsigned short* As[4];
    const unsigned short* Bs[4];
    int ldstA[4], ldstB[4];
#pragma unroll
    for (int j = 0; j < 4; ++j) {
        int ch = tid + j * 512;
        int row = ch >> 3, cpos = ch & 7;
        int scol = ((cpos ^ (row & 7)) << 3);
        As[j] = Ab + (size_t)row * K + scol;
        Bs[j] = Bb + (size_t)row * K + scol;
        ldstA[j] = ch * 16;
        ldstB[j] = 65536 + ch * 16;
    }

#define STG(bufi_, k0_) {                                                              \
    _Pragma("unroll")                                                                  \
    for (int j = 0; j < 4; ++j)                                                        \
        __builtin_amdgcn_global_load_lds(as_gbl(As[j] + (k0_)),                        \
            as_lds(smem + (bufi_) * 32768 + ldstA[j]), 16, 0, 0);                      \
    _Pragma("unroll")                                                                  \
    for (int j = 0; j < 4; ++j)                                                        \
        __builtin_amdgcn_global_load_lds(as_gbl(Bs[j] + (k0_)),                        \
            as_lds(smem + (bufi_) * 32768 + ldstB[j]), 16, 0, 0); }

    STG(0, 0);
    __syncthreads();

    for (int t = 0; t < 8; ++t) {
        const int cur = t & 1;
        if (t < 7) STG(cur ^ 1, (t + 1) * 64);
        const unsigned short* Ar = (const unsigned short*)(smem + cur * 32768);
        const unsigned short* Br = (const unsigned short*)(smem + cur * 32768 + 65536);
#pragma unroll
        for (int s = 0; s < 2; ++s) {
            bf16x8 bf[4], af[8];
#pragma unroll
            for (int n = 0; n < 4; ++n)
                bf[n] = ldsrd64(Br, wc * 64 + n * 16 + l15, s * 4 + g);
#pragma unroll
            for (int m = 0; m < 8; ++m)
                af[m] = ldsrd64(Ar, wr * 128 + m * 16 + l15, s * 4 + g);
            __builtin_amdgcn_s_setprio(1);
#pragma unroll
            for (int m = 0; m < 8; ++m)
#pragma unroll
                for (int n = 0; n < 4; ++n)
                    acc[m][n] = __builtin_amdgcn_mfma_f32_16x16x32_bf16(af[m], bf[n], acc[m][n], 0, 0, 0);
            __builtin_amdgcn_s_setprio(0);
        }
        __syncthreads();
    }
#undef STG

    const int mrow = mt * 256;
    const int ncol = nt * 256;
    float* Cl = (float*)smem;
    float bvj[4];
#pragma unroll
    for (int j = 0; j < 4; ++j) bvj[j] = bias[ncol + wc * 64 + j * 16 + l15];
    const int srow = tid >> 4;
    const int scol = (tid & 15) * 4;
    const float* Crd = Cl + srow * 258 + scol;
#pragma unroll
    for (int mc = 0; mc < 8; ++mc) {
        if (wr == (mc >> 2)) {
            int ibase = (mc & 3) * 2;
#pragma unroll
            for (int ii = 0; ii < 2; ++ii) {
                int i = ibase + ii;
                int lr = ii * 16 + g * 4;
#pragma unroll
                for (int j = 0; j < 4; ++j)
#pragma unroll
                    for (int rr = 0; rr < 4; ++rr)
                        Cl[(lr + rr) * 258 + wc * 64 + j * 16 + l15] = acc[i][j][rr] + bvj[j];
            }
        }
        __syncthreads();
        {
            float* gp = Cout + (size_t)(mrow + mc * 32 + srow) * N + ncol + scol;
#pragma unroll
            for (int it = 0; it < 4; ++it)
                *(float4*)(gp + it * 64) = *(const float4*)(Crd + it * 64);
        }
        __syncthreads();
    }
}

extern "C" void kernel_launch(void* const* d_in, const int* in_sizes, int n_in,
                              void* d_out, int out_size, void* d_ws, size_t ws_size,
                              hipStream_t stream)
{
    const int*           ids = (const int*)d_in[0];
    const unsigned char* pad = (const unsigned char*)d_in[1];
    const float*         tbl = (const float*)d_in[2];
    const float*         sfs = (const float*)d_in[3];
    const float*         als = (const float*)d_in[4];
    const float*         fw  = (const float*)d_in[5];
    const float*         fb  = (const float*)d_in[6];
    const float*         ow  = (const float*)d_in[7];
    const float*         ob  = (const float*)d_in[8];
    float* logits = (float*)d_out;

    // d_ws layout (60 MB)
    char* ws = (char*)d_ws;
    unsigned short* outw_bf = (unsigned short*)(ws);              // 32,768,000 B
    unsigned short* fusw_bf = (unsigned short*)(ws + 32768000);   //  2,097,152 B
    unsigned short* emb_bf  = (unsigned short*)(ws + 34865152);   //  4,194,304 B
    unsigned short* concat  = (unsigned short*)(ws + 39059456);   // 16,777,216 B
    unsigned short* fused   = (unsigned short*)(ws + 55836672);   //  4,194,304 B

    // scratch inside d_out (dead until final GEMM overwrites it)
    char* ob_scratch = (char*)d_out;
    unsigned short* P    = (unsigned short*)(ob_scratch);              // 67,108,864 B
    unsigned short* embT = (unsigned short*)(ob_scratch + 67108864);   //  4,194,304 B
    float*          dtab = (float*)(ob_scratch + 71303168);            //     32,768 B
    float*          lsum = (float*)(ob_scratch + 71335936);            //     65,536 B

    k_prep<<<6960, 256, 0, stream>>>(ids, tbl, als, fw, ow,
                                     outw_bf, fusw_bf, emb_bf, embT, dtab, lsum);

    dim3 bg(32, 32, BB);
    k_base<<<bg, 256, 0, stream>>>(emb_bf, pad, sfs, dtab, P, lsum);

    dim3 pg(64, BB, HH);
    k_pv<<<pg, 256, 0, stream>>>(P, embT, lsum, concat);

    k_gemm_bt<0><<<32 * 4, 256, 0, stream>>>(concat, fusw_bf, fb, fused, BB * SB, DD, HH * DD);
    k_logits<<<16 * 125, 512, 0, stream>>>(fused, outw_bf, ob, logits, BB * SB, VV, DD);
}

// Round 14
// 357.516 us; speedup vs baseline: 1.1736x; 1.0282x over previous
//
#include <hip/hip_runtime.h>
#include <hip/hip_bf16.h>
#include <stdint.h>

#define BB 2
#define SB 2048
#define DD 512
#define HH 4
#define VV 32000

typedef __attribute__((ext_vector_type(4))) float f32x4;
typedef __attribute__((ext_vector_type(8))) short bf16x8;
typedef __attribute__((ext_vector_type(4))) unsigned short us4;

__device__ __forceinline__ unsigned short f2bf(float f) {
    unsigned u = __float_as_uint(f);
    u += 0x7fffu + ((u >> 16) & 1u);
    return (unsigned short)(u >> 16);
}

__device__ __forceinline__ __attribute__((address_space(3))) unsigned int*
as_lds(void* p) {
    return (__attribute__((address_space(3))) unsigned int*)(unsigned)(uintptr_t)p;
}
__device__ __forceinline__ const __attribute__((address_space(1))) unsigned int*
as_gbl(const void* p) {
    return (const __attribute__((address_space(1))) unsigned int*)(uintptr_t)p;
}

// swizzled read from a [rows][64] bf16 LDS tile (128B rows): logical 16B-chunk c
// lives at slot c^(row&7). 2-way residual conflict (free).
__device__ __forceinline__ bf16x8 ldsrd64(const unsigned short* base, int row, int c) {
    return *(const bf16x8*)((const char*)base + row * 128 + ((c ^ (row & 7)) << 4));
}

// ---------------- merged prep kernel ----------------
__global__ void k_prep(const int* __restrict__ ids, const float* __restrict__ tbl,
                       const float* __restrict__ als,
                       const float* __restrict__ fw, const float* __restrict__ ow,
                       unsigned short* __restrict__ outw_bf, unsigned short* __restrict__ fusw_bf,
                       unsigned short* __restrict__ emb, unsigned short* __restrict__ embT,
                       float* __restrict__ dtab, float* __restrict__ lsum)
{
    __shared__ unsigned short TT[64][72];
    const int bid = blockIdx.x, t = threadIdx.x;

    if (bid < 2000) {
        int base = bid * 8192 + t * 4;
#pragma unroll
        for (int it = 0; it < 8; ++it) {
            int i = base + it * 1024;
            float4 v = *(const float4*)(ow + i);
            us4 o; o.x = f2bf(v.x); o.y = f2bf(v.y); o.z = f2bf(v.z); o.w = f2bf(v.w);
            *(us4*)(outw_bf + i) = o;
        }
    } else if (bid < 2256) {
        int base = (bid - 2000) * 4096 + t * 4;
#pragma unroll
        for (int it = 0; it < 4; ++it) {
            int i = base + it * 1024;
            float4 v = *(const float4*)(fw + i);
            us4 o; o.x = f2bf(v.x); o.y = f2bf(v.y); o.z = f2bf(v.z); o.w = f2bf(v.w);
            *(us4*)(fusw_bf + i) = o;
        }
    } else if (bid < 6352) {
        int row = bid - 2256;
        int id = ids[row];
        if (id < 0) id = 0;
        if (id >= VV) id = VV - 1;
        const float* s = tbl + (size_t)id * DD;
        unsigned short* d = emb + (size_t)row * DD;
        d[t]       = f2bf(s[t]);
        d[t + 256] = f2bf(s[t + 256]);
    } else if (bid < 6448) {
        int i = (bid - 6352) * 256 + t;
        if (i < HH * SB) {
            int h = i >> 11, dd = i & (SB - 1);
            dtab[i] = 0.04419417382415922f / (1.f + als[h] * (float)dd);
        } else {
            lsum[i - HH * SB] = 0.f;
        }
    } else {
        int bid2 = bid - 6448;
        const int d0 = (bid2 & 7) * 64, s0 = ((bid2 >> 3) & 31) * 64, b = bid2 >> 8;
        {
            int s = t >> 2, c16 = (t & 3) * 16;
            int id = ids[b * SB + s0 + s];
            if (id < 0) id = 0;
            if (id >= VV) id = VV - 1;
            const float* src = tbl + (size_t)id * DD + d0 + c16;
#pragma unroll
            for (int q4 = 0; q4 < 4; ++q4) {
                float4 v = *(const float4*)(src + q4 * 4);
                TT[c16 + q4 * 4 + 0][s] = f2bf(v.x);
                TT[c16 + q4 * 4 + 1][s] = f2bf(v.y);
                TT[c16 + q4 * 4 + 2][s] = f2bf(v.z);
                TT[c16 + q4 * 4 + 3][s] = f2bf(v.w);
            }
        }
        __syncthreads();
        {
            int d = t >> 2, sc = (t & 3) * 16;
            bf16x8 o0, o1;
#pragma unroll
            for (int j = 0; j < 8; ++j) {
                o0[j] = (short)TT[d][sc + j];
                o1[j] = (short)TT[d][sc + 8 + j];
            }
            unsigned short* dst = embT + ((size_t)(b * DD + d0 + d)) * SB + s0 + sc;
            *(bf16x8*)dst = o0;
            *(bf16x8*)(dst + 8) = o1;
        }
    }
}

// ---------------- phase 2: shared base QK^T, dc-double-buffered ----------------
__launch_bounds__(256, 2)
__global__ void k_base(const unsigned short* __restrict__ emb,
                       const unsigned char* __restrict__ pad,
                       const float* __restrict__ sfs,
                       const float* __restrict__ als,
                       const float* __restrict__ dtab,
                       unsigned short* __restrict__ P,      // [4][2][2048][2048]
                       float* __restrict__ lsum)            // [4][2][2048]
{
    const int kt = blockIdx.x, qt = blockIdx.y, b = blockIdx.z;
    if (kt > qt + 1) return;
    const int tid = threadIdx.x, lane = tid & 63, wv = tid >> 6;
    const int l15 = lane & 15, g = lane >> 4;

    if (kt == qt + 1) {
        int row = tid >> 2, cb = (tid & 3) * 16;
        int4 z = {0, 0, 0, 0};
#pragma unroll
        for (int h = 0; h < 4; ++h) {
            unsigned short* Ph = P + (((size_t)(h * 2 + b)) * SB + qt * 64 + row) * SB + kt * 64 + cb;
            *(int4*)Ph = z;
            *(int4*)(Ph + 8) = z;
        }
        return;
    }

    __shared__ __align__(16) unsigned short Ql[2][64 * 128];
    __shared__ __align__(16) unsigned short Kl[2][64 * 128];

    const int q = qt * 64 + wv * 16 + l15;
    const bool dup = (sfs[0] == sfs[3]) && (als[0] == als[3]);   // head3 == head0

#define STAGEB(buf_, dc_) {                                                            \
    _Pragma("unroll")                                                                  \
    for (int i = 0; i < 4; ++i) {                                                      \
        int flat = (i * 256 + tid) * 8;                                                \
        int row = flat >> 7;                                                           \
        int ch  = (flat >> 3) & 15;                                                    \
        int scol = ((ch ^ (row & 15)) << 3);                                           \
        __builtin_amdgcn_global_load_lds(                                              \
            as_gbl(emb + ((size_t)(b * SB + qt * 64 + row)) * DD + (dc_) * 128 + scol),\
            as_lds(Ql[buf_] + flat), 16, 0, 0);                                        \
        __builtin_amdgcn_global_load_lds(                                              \
            as_gbl(emb + ((size_t)(b * SB + kt * 64 + row)) * DD + (dc_) * 128 + scol),\
            as_lds(Kl[buf_] + flat), 16, 0, 0);                                        \
    } }

    f32x4 zero4 = {0.f, 0.f, 0.f, 0.f};
    f32x4 cc[4];
#pragma unroll
    for (int c = 0; c < 4; ++c) cc[c] = zero4;

    STAGEB(0, 0);
    __syncthreads();
    for (int dc = 0; dc < 4; ++dc) {
        const int cur = dc & 1;
        if (dc < 3) STAGEB(cur ^ 1, dc + 1);
#pragma unroll
        for (int dsl = 0; dsl < 4; ++dsl) {
            int chr = (dsl * 4 + g);
            bf16x8 qf = *(const bf16x8*)(Ql[cur] + (wv * 16 + l15) * 128 + ((chr ^ l15) << 3));
#pragma unroll
            for (int c = 0; c < 4; ++c) {
                bf16x8 kf = *(const bf16x8*)(Kl[cur] + (c * 16 + l15) * 128 + ((chr ^ l15) << 3));
                cc[c] = __builtin_amdgcn_mfma_f32_16x16x32_bf16(kf, qf, cc[c], 0, 0, 0);
            }
        }
        __syncthreads();
    }
#undef STAGEB

    unsigned long long padm = __ballot(pad[(size_t)b * SB + kt * 64 + lane] != 0);

    const int wins[4] = {1 << 30, 128, 512, 1 << 30};
#pragma unroll
    for (int h = 0; h < 4; ++h) {
        if (h == 3 && dup) continue;                      // P[3] == P[0], never read
        const int win = wins[h];
        if (kt * 64 + win + 192 < qt * 64) continue;
        const float sf = sfs[h];
        const float* dth = dtab + h * SB;
        float rsum = 0.f;
        unsigned short pb[4][4];
#pragma unroll
        for (int c = 0; c < 4; ++c) {
#pragma unroll
            for (int r = 0; r < 4; ++r) {
                int kk = kt * 64 + c * 16 + 4 * g + r;
                int dist = q - kk;
                float p = 0.f;
                if (dist >= 0 && dist <= win &&
                    ((dist == 0) || !((padm >> (c * 16 + 4 * g + r)) & 1ull))) {
                    float s = cc[c][r] * dth[dist];
                    if (dist == 0) s *= sf;
                    p = __expf(s);
                }
                rsum += p;
                pb[c][r] = f2bf(p);
            }
        }
        unsigned short* Ph = P + (((size_t)(h * 2 + b)) * SB + q) * SB + kt * 64;
#pragma unroll
        for (int c = 0; c < 4; ++c) {
            us4 o;
            o.x = pb[c][0]; o.y = pb[c][1]; o.z = pb[c][2]; o.w = pb[c][3];
            *(us4*)(Ph + c * 16 + 4 * g) = o;
        }
        rsum += __shfl_xor(rsum, 16, 64);
        rsum += __shfl_xor(rsum, 32, 64);
        if (lane < 16)
            atomicAdd(&lsum[((size_t)(h * 2 + b)) * SB + q], rsum);
    }
}

// ---------------- phase 3: ctx = P * V^T, BK=64 double-buffered; h3 dedup ----------------
__launch_bounds__(256, 2)
__global__ void k_pv(const unsigned short* __restrict__ P,
                     const unsigned short* __restrict__ embT,
                     const float* __restrict__ lsum,
                     const float* __restrict__ sfs,
                     const float* __restrict__ als,
                     unsigned short* __restrict__ concat)
{
    const int t64 = blockIdx.x, b = blockIdx.y, h = blockIdx.z;
    const bool dup = (sfs[0] == sfs[3]) && (als[0] == als[3]);
    if (h == 3 && dup) return;                     // h0 block writes h3's columns
    const int mt = t64 >> 2, nt = t64 & 3;
    const int Q0 = mt * 128;
    const int win = (h == 1) ? 128 : (h == 2) ? 512 : (1 << 30);
    int klo = Q0 - win - 64; if (klo < 0) klo = 0; klo &= ~63;
    const int khi = Q0 + 128;
    const int nsteps = (khi - klo) >> 6;

    __shared__ __align__(16) unsigned short Pl[2][128 * 64];
    __shared__ __align__(16) unsigned short Vl[2][128 * 64];

    const int tid = threadIdx.x, lane = tid & 63, wv = tid >> 6;
    const int wm = (wv >> 1) * 64, wn = (wv & 1) * 64;
    const int l15 = lane & 15, g = lane >> 4;

    f32x4 zero4 = {0.f, 0.f, 0.f, 0.f};
    f32x4 acc[4][4];
#pragma unroll
    for (int i = 0; i < 4; ++i)
#pragma unroll
        for (int j = 0; j < 4; ++j) acc[i][j] = zero4;

    const unsigned short* Ab = P + (((size_t)(h * 2 + b)) * SB + Q0) * SB;
    const unsigned short* Bb = embT + ((size_t)(b * DD + nt * 128)) * SB;

    const unsigned short* Ps[4];
    const unsigned short* Vs[4];
    int ldst[4];
#pragma unroll
    for (int j = 0; j < 4; ++j) {
        int ch = j * 256 + tid;
        int row = ch >> 3, cpos = ch & 7;
        int scol = ((cpos ^ (row & 7)) << 3);
        Ps[j] = Ab + (size_t)row * SB + scol;
        Vs[j] = Bb + (size_t)row * SB + scol;
        ldst[j] = ch * 16;
    }

#define STAGEPV(buf_, k0_) {                                                           \
    _Pragma("unroll")                                                                  \
    for (int j = 0; j < 4; ++j) {                                                      \
        __builtin_amdgcn_global_load_lds(as_gbl(Ps[j] + (k0_)),                        \
            as_lds((char*)Pl[buf_] + ldst[j]), 16, 0, 0);                              \
        __builtin_amdgcn_global_load_lds(as_gbl(Vs[j] + (k0_)),                        \
            as_lds((char*)Vl[buf_] + ldst[j]), 16, 0, 0);                              \
    } }

    STAGEPV(0, klo);
    __syncthreads();
    for (int t = 0; t < nsteps; ++t) {
        const int cur = t & 1;
        if (t + 1 < nsteps) STAGEPV(cur ^ 1, klo + (t + 1) * 64);
#pragma unroll
        for (int s = 0; s < 2; ++s) {
            bf16x8 af[4], bfr[4];
#pragma unroll
            for (int i = 0; i < 4; ++i) {
                af[i]  = ldsrd64(Pl[cur], wm + i * 16 + l15, s * 4 + g);
                bfr[i] = ldsrd64(Vl[cur], wn + i * 16 + l15, s * 4 + g);
            }
#pragma unroll
            for (int i = 0; i < 4; ++i)
#pragma unroll
                for (int j = 0; j < 4; ++j)
                    acc[i][j] = __builtin_amdgcn_mfma_f32_16x16x32_bf16(af[i], bfr[j], acc[i][j], 0, 0, 0);
        }
        __syncthreads();
    }
#undef STAGEPV

    const float* ls = lsum + ((size_t)(h * 2 + b)) * SB;
    unsigned short* cb  = concat + ((size_t)(b * SB)) * (HH * DD) + h * DD + nt * 128;
    unsigned short* cb3 = concat + ((size_t)(b * SB)) * (HH * DD) + 3 * DD + nt * 128;
    const bool wr3 = (h == 0) && dup;
#pragma unroll
    for (int i = 0; i < 4; ++i) {
        int rowb = wm + i * 16 + g * 4;
        float inv[4];
#pragma unroll
        for (int rr = 0; rr < 4; ++rr) inv[rr] = 1.f / ls[Q0 + rowb + rr];
#pragma unroll
        for (int j = 0; j < 4; ++j) {
            int col = wn + j * 16 + l15;
#pragma unroll
            for (int rr = 0; rr < 4; ++rr) {
                unsigned short v = f2bf(acc[i][j][rr] * inv[rr]);
                cb[(size_t)(Q0 + rowb + rr) * (HH * DD) + col] = v;
                if (wr3) cb3[(size_t)(Q0 + rowb + rr) * (HH * DD) + col] = v;
            }
        }
    }
}

// ---------------- fusion GEMM: 128x128, BK=32 double-buffered ----------------
template <int OUTF32>
__launch_bounds__(256, 2)
__global__ void k_gemm_bt(const unsigned short* __restrict__ A,
                          const unsigned short* __restrict__ Bt,
                          const float* __restrict__ bias,
                          void* __restrict__ Cout,
                          int M, int N, int K)
{
    const int nMt = M >> 7;
    const int nwg = gridDim.x;
    int bid = blockIdx.x;
    int q = nwg >> 3, r = nwg & 7;
    int x = bid & 7, o = bid >> 3;
    int wg = (x < r ? x * (q + 1) : r * (q + 1) + (x - r) * q) + o;
    const int mt = wg % nMt, nt = wg / nMt;

    __shared__ __align__(16) unsigned short Al[2][128 * 32];
    __shared__ __align__(16) unsigned short Bl[2][128 * 32];

    const int tid = threadIdx.x;
    const int lane = tid & 63;
    const int wv = tid >> 6;
    const int wm = (wv >> 1) * 64, wn = (wv & 1) * 64;
    const int l15 = lane & 15, g = lane >> 4;

    f32x4 zero4 = {0.f, 0.f, 0.f, 0.f};
    f32x4 acc[4][4];
#pragma unroll
    for (int i = 0; i < 4; ++i)
#pragma unroll
        for (int j = 0; j < 4; ++j) acc[i][j] = zero4;

    const unsigned short* Ab = A + (size_t)mt * 128 * K;
    const unsigned short* Bb = Bt + (size_t)nt * 128 * K;

#define STAGEF(buf_, k0_) {                                                            \
    _Pragma("unroll")                                                                  \
    for (int s = 0; s < 2; ++s) {                                                      \
        int e = (s * 256 + tid) * 8;                                                   \
        int row = e >> 5, col = e & 31;                                                \
        __builtin_amdgcn_global_load_lds(as_gbl(Ab + (size_t)row * K + (k0_) + col),   \
                                         as_lds(Al[buf_] + e), 16, 0, 0);              \
        __builtin_amdgcn_global_load_lds(as_gbl(Bb + (size_t)row * K + (k0_) + col),   \
                                         as_lds(Bl[buf_] + e), 16, 0, 0);              \
    } }

    const int nk = K >> 5;
    STAGEF(0, 0);
    __syncthreads();
    for (int t = 0; t < nk; ++t) {
        const int cur = t & 1;
        if (t + 1 < nk) STAGEF(cur ^ 1, (t + 1) * 32);
        bf16x8 af[4], bfr[4];
#pragma unroll
        for (int i = 0; i < 4; ++i) {
            af[i]  = *(const bf16x8*)(Al[cur] + (wm + i * 16 + l15) * 32 + 8 * g);
            bfr[i] = *(const bf16x8*)(Bl[cur] + (wn + i * 16 + l15) * 32 + 8 * g);
        }
#pragma unroll
        for (int i = 0; i < 4; ++i)
#pragma unroll
            for (int j = 0; j < 4; ++j)
                acc[i][j] = __builtin_amdgcn_mfma_f32_16x16x32_bf16(af[i], bfr[j], acc[i][j], 0, 0, 0);
        __syncthreads();
    }
#undef STAGEF

#pragma unroll
    for (int i = 0; i < 4; ++i) {
        int rowb = mt * 128 + wm + i * 16 + g * 4;
#pragma unroll
        for (int j = 0; j < 4; ++j) {
            int col = nt * 128 + wn + j * 16 + l15;
            float bv = bias[col];
            if (OUTF32) {
                float* C = (float*)Cout;
#pragma unroll
                for (int rr = 0; rr < 4; ++rr)
                    C[(size_t)(rowb + rr) * N + col] = acc[i][j][rr] + bv;
            } else {
                unsigned short* C = (unsigned short*)Cout;
#pragma unroll
                for (int rr = 0; rr < 4; ++rr)
                    C[(size_t)(rowb + rr) * N + col] = f2bf(acc[i][j][rr] + bv);
            }
        }
    }
}

// ---------------- logits GEMM: R7-exact (256x256, BK=64 dbuf, LDS epilogue) ----------
__launch_bounds__(512, 1)
__global__ void k_logits(const unsigned short* __restrict__ A,
                         const unsigned short* __restrict__ Bt,
                         const float* __restrict__ bias,
                         float* __restrict__ Cout,
                         int M, int N, int K)
{
    const int nMt = M >> 8;
    const int nwg = gridDim.x;
    int bid = blockIdx.x;
    int q = nwg >> 3, r = nwg & 7;
    int x = bid & 7, o = bid >> 3;
    int wg = (x < r ? x * (q + 1) : r * (q + 1) + (x - r) * q) + o;
    const int mt = wg % nMt, nt = wg / nMt;

    __shared__ __align__(16) char smem[131072];

    const int tid = threadIdx.x, lane = tid & 63, wv = tid >> 6;
    const int wr = wv >> 2, wc = wv & 3;
    const int l15 = lane & 15, g = lane >> 4;

    f32x4 zero4 = {0.f, 0.f, 0.f, 0.f};
    f32x4 acc[8][4];
#pragma unroll
    for (int i = 0; i < 8; ++i)
#pragma unroll
        for (int j = 0; j < 4; ++j) acc[i][j] = zero4;

    const unsigned short* Ab = A + (size_t)mt * 256 * K;
    const unsigned short* Bb = Bt + (size_t)nt * 256 * K;

    const unsigned short* As[4];
    const unsigned short* Bs[4];
    int ldstA[4], ldstB[4];
#pragma unroll
    for (int j = 0; j < 4; ++j) {
        int ch = tid + j * 512;
        int row = ch >> 3, cpos = ch & 7;
        int scol = ((cpos ^ (row & 7)) << 3);
        As[j] = Ab + (size_t)row * K + scol;
        Bs[j] = Bb + (size_t)row * K + scol;
        ldstA[j] = ch * 16;
        ldstB[j] = 65536 + ch * 16;
    }

#define STG(bufi_, k0_) {                                                              \
    _Pragma("unroll")                                                                  \
    for (int j = 0; j < 4; ++j)                                                        \
        __builtin_amdgcn_global_load_lds(as_gbl(As[j] + (k0_)),                        \
            as_lds(smem + (bufi_) * 32768 + ldstA[j]), 16, 0, 0);                      \
    _Pragma("unroll")                                                                  \
    for (int j = 0; j < 4; ++j)                                                        \
        __builtin_amdgcn_global_load_lds(as_gbl(Bs[j] + (k0_)),                        \
            as_lds(smem + (bufi_) * 32768 + ldstB[j]), 16, 0, 0); }

    STG(0, 0);
    __syncthreads();

    for (int t = 0; t < 8; ++t) {
        const int cur = t & 1;
        if (t < 7) STG(cur ^ 1, (t + 1) * 64);
        const unsigned short* Ar = (const unsigned short*)(smem + cur * 32768);
        const unsigned short* Br = (const unsigned short*)(smem + cur * 32768 + 65536);
#pragma unroll
        for (int s = 0; s < 2; ++s) {
            bf16x8 bf[4], af[8];
#pragma unroll
            for (int n = 0; n < 4; ++n)
                bf[n] = ldsrd64(Br, wc * 64 + n * 16 + l15, s * 4 + g);
#pragma unroll
            for (int m = 0; m < 8; ++m)
                af[m] = ldsrd64(Ar, wr * 128 + m * 16 + l15, s * 4 + g);
            __builtin_amdgcn_s_setprio(1);
#pragma unroll
            for (int m = 0; m < 8; ++m)
#pragma unroll
                for (int n = 0; n < 4; ++n)
                    acc[m][n] = __builtin_amdgcn_mfma_f32_16x16x32_bf16(af[m], bf[n], acc[m][n], 0, 0, 0);
            __builtin_amdgcn_s_setprio(0);
        }
        __syncthreads();
    }
#undef STG

    const int mrow = mt * 256;
    const int ncol = nt * 256;
    float* Cl = (float*)smem;
    float bvj[4];
#pragma unroll
    for (int j = 0; j < 4; ++j) bvj[j] = bias[ncol + wc * 64 + j * 16 + l15];
    const int srow = tid >> 4;
    const int scol = (tid & 15) * 4;
    const float* Crd = Cl + srow * 258 + scol;
#pragma unroll
    for (int mc = 0; mc < 8; ++mc) {
        if (wr == (mc >> 2)) {
            int ibase = (mc & 3) * 2;
#pragma unroll
            for (int ii = 0; ii < 2; ++ii) {
                int i = ibase + ii;
                int lr = ii * 16 + g * 4;
#pragma unroll
                for (int j = 0; j < 4; ++j)
#pragma unroll
                    for (int rr = 0; rr < 4; ++rr)
                        Cl[(lr + rr) * 258 + wc * 64 + j * 16 + l15] = acc[i][j][rr] + bvj[j];
            }
        }
        __syncthreads();
        {
            float* gp = Cout + (size_t)(mrow + mc * 32 + srow) * N + ncol + scol;
#pragma unroll
            for (int it = 0; it < 4; ++it)
                *(float4*)(gp + it * 64) = *(const float4*)(Crd + it * 64);
        }
        __syncthreads();
    }
}

extern "C" void kernel_launch(void* const* d_in, const int* in_sizes, int n_in,
                              void* d_out, int out_size, void* d_ws, size_t ws_size,
                              hipStream_t stream)
{
    const int*           ids = (const int*)d_in[0];
    const unsigned char* pad = (const unsigned char*)d_in[1];
    const float*         tbl = (const float*)d_in[2];
    const float*         sfs = (const float*)d_in[3];
    const float*         als = (const float*)d_in[4];
    const float*         fw  = (const float*)d_in[5];
    const float*         fb  = (const float*)d_in[6];
    const float*         ow  = (const float*)d_in[7];
    const float*         ob  = (const float*)d_in[8];
    float* logits = (float*)d_out;

    // d_ws layout (60 MB)
    char* ws = (char*)d_ws;
    unsigned short* outw_bf = (unsigned short*)(ws);              // 32,768,000 B
    unsigned short* fusw_bf = (unsigned short*)(ws + 32768000);   //  2,097,152 B
    unsigned short* emb_bf  = (unsigned short*)(ws + 34865152);   //  4,194,304 B
    unsigned short* concat  = (unsigned short*)(ws + 39059456);   // 16,777,216 B
    unsigned short* fused   = (unsigned short*)(ws + 55836672);   //  4,194,304 B

    // scratch inside d_out (dead until final GEMM overwrites it)
    char* ob_scratch = (char*)d_out;
    unsigned short* P    = (unsigned short*)(ob_scratch);              // 67,108,864 B
    unsigned short* embT = (unsigned short*)(ob_scratch + 67108864);   //  4,194,304 B
    float*          dtab = (float*)(ob_scratch + 71303168);            //     32,768 B
    float*          lsum = (float*)(ob_scratch + 71335936);            //     65,536 B

    k_prep<<<6960, 256, 0, stream>>>(ids, tbl, als, fw, ow,
                                     outw_bf, fusw_bf, emb_bf, embT, dtab, lsum);

    dim3 bg(32, 32, BB);
    k_base<<<bg, 256, 0, stream>>>(emb_bf, pad, sfs, als, dtab, P, lsum);

    dim3 pg(64, BB, HH);
    k_pv<<<pg, 256, 0, stream>>>(P, embT, lsum, sfs, als, concat);

    k_gemm_bt<0><<<32 * 4, 256, 0, stream>>>(concat, fusw_bf, fb, fused, BB * SB, DD, HH * DD);
    k_logits<<<16 * 125, 512, 0, stream>>>(fused, outw_bf, ob, logits, BB * SB, VV, DD);
}

// Round 15
// 342.253 us; speedup vs baseline: 1.2260x; 1.0446x over previous
//
#include <hip/hip_runtime.h>
#include <hip/hip_bf16.h>
#include <stdint.h>

#define BB 2
#define SB 2048
#define DD 512
#define HH 4
#define VV 32000

typedef __attribute__((ext_vector_type(4))) float f32x4;
typedef __attribute__((ext_vector_type(8))) short bf16x8;
typedef __attribute__((ext_vector_type(4))) unsigned short us4;

__device__ __forceinline__ unsigned short f2bf(float f) {
    unsigned u = __float_as_uint(f);
    u += 0x7fffu + ((u >> 16) & 1u);
    return (unsigned short)(u >> 16);
}

__device__ __forceinline__ __attribute__((address_space(3))) unsigned int*
as_lds(void* p) {
    return (__attribute__((address_space(3))) unsigned int*)(unsigned)(uintptr_t)p;
}
__device__ __forceinline__ const __attribute__((address_space(1))) unsigned int*
as_gbl(const void* p) {
    return (const __attribute__((address_space(1))) unsigned int*)(uintptr_t)p;
}

// swizzled read from a [rows][64] bf16 LDS tile (128B rows): logical 16B-chunk c
// lives at slot c^(row&7). 2-way residual conflict (free).
__device__ __forceinline__ bf16x8 ldsrd64(const unsigned short* base, int row, int c) {
    return *(const bf16x8*)((const char*)base + row * 128 + ((c ^ (row & 7)) << 4));
}

// ---------------- merged prep kernel ----------------
__global__ void k_prep(const int* __restrict__ ids, const float* __restrict__ tbl,
                       const float* __restrict__ als,
                       const float* __restrict__ fw, const float* __restrict__ ow,
                       unsigned short* __restrict__ outw_bf, unsigned short* __restrict__ fusw_bf,
                       unsigned short* __restrict__ emb, unsigned short* __restrict__ embT,
                       float* __restrict__ dtab, float* __restrict__ lsum)
{
    __shared__ unsigned short TT[64][72];
    const int bid = blockIdx.x, t = threadIdx.x;

    if (bid < 2000) {
        int base = bid * 8192 + t * 4;
#pragma unroll
        for (int it = 0; it < 8; ++it) {
            int i = base + it * 1024;
            float4 v = *(const float4*)(ow + i);
            us4 o; o.x = f2bf(v.x); o.y = f2bf(v.y); o.z = f2bf(v.z); o.w = f2bf(v.w);
            *(us4*)(outw_bf + i) = o;
        }
    } else if (bid < 2256) {
        int base = (bid - 2000) * 4096 + t * 4;
#pragma unroll
        for (int it = 0; it < 4; ++it) {
            int i = base + it * 1024;
            float4 v = *(const float4*)(fw + i);
            us4 o; o.x = f2bf(v.x); o.y = f2bf(v.y); o.z = f2bf(v.z); o.w = f2bf(v.w);
            *(us4*)(fusw_bf + i) = o;
        }
    } else if (bid < 6352) {
        int row = bid - 2256;
        int id = ids[row];
        if (id < 0) id = 0;
        if (id >= VV) id = VV - 1;
        const float* s = tbl + (size_t)id * DD;
        unsigned short* d = emb + (size_t)row * DD;
        d[t]       = f2bf(s[t]);
        d[t + 256] = f2bf(s[t + 256]);
    } else if (bid < 6448) {
        int i = (bid - 6352) * 256 + t;
        if (i < HH * SB) {
            int h = i >> 11, dd = i & (SB - 1);
            dtab[i] = 0.04419417382415922f / (1.f + als[h] * (float)dd);
        } else {
            lsum[i - HH * SB] = 0.f;
        }
    } else {
        int bid2 = bid - 6448;
        const int d0 = (bid2 & 7) * 64, s0 = ((bid2 >> 3) & 31) * 64, b = bid2 >> 8;
        {
            int s = t >> 2, c16 = (t & 3) * 16;
            int id = ids[b * SB + s0 + s];
            if (id < 0) id = 0;
            if (id >= VV) id = VV - 1;
            const float* src = tbl + (size_t)id * DD + d0 + c16;
#pragma unroll
            for (int q4 = 0; q4 < 4; ++q4) {
                float4 v = *(const float4*)(src + q4 * 4);
                TT[c16 + q4 * 4 + 0][s] = f2bf(v.x);
                TT[c16 + q4 * 4 + 1][s] = f2bf(v.y);
                TT[c16 + q4 * 4 + 2][s] = f2bf(v.z);
                TT[c16 + q4 * 4 + 3][s] = f2bf(v.w);
            }
        }
        __syncthreads();
        {
            int d = t >> 2, sc = (t & 3) * 16;
            bf16x8 o0, o1;
#pragma unroll
            for (int j = 0; j < 8; ++j) {
                o0[j] = (short)TT[d][sc + j];
                o1[j] = (short)TT[d][sc + 8 + j];
            }
            unsigned short* dst = embT + ((size_t)(b * DD + d0 + d)) * SB + s0 + sc;
            *(bf16x8*)dst = o0;
            *(bf16x8*)(dst + 8) = o1;
        }
    }
}

// ---------------- phase 2: shared base QK^T, dc-double-buffered ----------------
__launch_bounds__(256, 2)
__global__ void k_base(const unsigned short* __restrict__ emb,
                       const unsigned char* __restrict__ pad,
                       const float* __restrict__ sfs,
                       const float* __restrict__ als,
                       const float* __restrict__ dtab,
                       unsigned short* __restrict__ P,      // [4][2][2048][2048]
                       float* __restrict__ lsum)            // [4][2][2048]
{
    const int kt = blockIdx.x, qt = blockIdx.y, b = blockIdx.z;
    if (kt > qt + 1) return;
    const int tid = threadIdx.x, lane = tid & 63, wv = tid >> 6;
    const int l15 = lane & 15, g = lane >> 4;

    if (kt == qt + 1) {
        int row = tid >> 2, cb = (tid & 3) * 16;
        int4 z = {0, 0, 0, 0};
#pragma unroll
        for (int h = 0; h < 4; ++h) {
            unsigned short* Ph = P + (((size_t)(h * 2 + b)) * SB + qt * 64 + row) * SB + kt * 64 + cb;
            *(int4*)Ph = z;
            *(int4*)(Ph + 8) = z;
        }
        return;
    }

    __shared__ __align__(16) unsigned short Ql[2][64 * 128];
    __shared__ __align__(16) unsigned short Kl[2][64 * 128];

    const int q = qt * 64 + wv * 16 + l15;
    const bool dup = (sfs[0] == sfs[3]) && (als[0] == als[3]);   // head3 == head0

#define STAGEB(buf_, dc_) {                                                            \
    _Pragma("unroll")                                                                  \
    for (int i = 0; i < 4; ++i) {                                                      \
        int flat = (i * 256 + tid) * 8;                                                \
        int row = flat >> 7;                                                           \
        int ch  = (flat >> 3) & 15;                                                    \
        int scol = ((ch ^ (row & 15)) << 3);                                           \
        __builtin_amdgcn_global_load_lds(                                              \
            as_gbl(emb + ((size_t)(b * SB + qt * 64 + row)) * DD + (dc_) * 128 + scol),\
            as_lds(Ql[buf_] + flat), 16, 0, 0);                                        \
        __builtin_amdgcn_global_load_lds(                                              \
            as_gbl(emb + ((size_t)(b * SB + kt * 64 + row)) * DD + (dc_) * 128 + scol),\
            as_lds(Kl[buf_] + flat), 16, 0, 0);                                        \
    } }

    f32x4 zero4 = {0.f, 0.f, 0.f, 0.f};
    f32x4 cc[4];
#pragma unroll
    for (int c = 0; c < 4; ++c) cc[c] = zero4;

    STAGEB(0, 0);
    __syncthreads();
    for (int dc = 0; dc < 4; ++dc) {
        const int cur = dc & 1;
        if (dc < 3) STAGEB(cur ^ 1, dc + 1);
#pragma unroll
        for (int dsl = 0; dsl < 4; ++dsl) {
            int chr = (dsl * 4 + g);
            bf16x8 qf = *(const bf16x8*)(Ql[cur] + (wv * 16 + l15) * 128 + ((chr ^ l15) << 3));
#pragma unroll
            for (int c = 0; c < 4; ++c) {
                bf16x8 kf = *(const bf16x8*)(Kl[cur] + (c * 16 + l15) * 128 + ((chr ^ l15) << 3));
                cc[c] = __builtin_amdgcn_mfma_f32_16x16x32_bf16(kf, qf, cc[c], 0, 0, 0);
            }
        }
        __syncthreads();
    }
#undef STAGEB

    unsigned long long padm = __ballot(pad[(size_t)b * SB + kt * 64 + lane] != 0);

    const int wins[4] = {1 << 30, 128, 512, 1 << 30};
#pragma unroll
    for (int h = 0; h < 4; ++h) {
        if (h == 3 && dup) continue;                      // P[3] == P[0], never read
        const int win = wins[h];
        if (kt * 64 + win + 192 < qt * 64) continue;
        const float sf = sfs[h];
        const float* dth = dtab + h * SB;
        float rsum = 0.f;
        unsigned short pb[4][4];
#pragma unroll
        for (int c = 0; c < 4; ++c) {
#pragma unroll
            for (int r = 0; r < 4; ++r) {
                int kk = kt * 64 + c * 16 + 4 * g + r;
                int dist = q - kk;
                float p = 0.f;
                if (dist >= 0 && dist <= win &&
                    ((dist == 0) || !((padm >> (c * 16 + 4 * g + r)) & 1ull))) {
                    float s = cc[c][r] * dth[dist];
                    if (dist == 0) s *= sf;
                    p = __expf(s);
                }
                rsum += p;
                pb[c][r] = f2bf(p);
            }
        }
        unsigned short* Ph = P + (((size_t)(h * 2 + b)) * SB + q) * SB + kt * 64;
#pragma unroll
        for (int c = 0; c < 4; ++c) {
            us4 o;
            o.x = pb[c][0]; o.y = pb[c][1]; o.z = pb[c][2]; o.w = pb[c][3];
            *(us4*)(Ph + c * 16 + 4 * g) = o;
        }
        rsum += __shfl_xor(rsum, 16, 64);
        rsum += __shfl_xor(rsum, 32, 64);
        if (lane < 16)
            atomicAdd(&lsum[((size_t)(h * 2 + b)) * SB + q], rsum);
    }
}

// ---------------- phase 3: ctx = P * V^T, BK=64 double-buffered; h3 dedup ----------------
__launch_bounds__(256, 2)
__global__ void k_pv(const unsigned short* __restrict__ P,
                     const unsigned short* __restrict__ embT,
                     const float* __restrict__ lsum,
                     const float* __restrict__ sfs,
                     const float* __restrict__ als,
                     unsigned short* __restrict__ concat)
{
    const int t64 = blockIdx.x, b = blockIdx.y, h = blockIdx.z;
    const bool dup = (sfs[0] == sfs[3]) && (als[0] == als[3]);
    if (h == 3 && dup) return;                     // h0 block writes h3's columns
    const int mt = t64 >> 2, nt = t64 & 3;
    const int Q0 = mt * 128;
    const int win = (h == 1) ? 128 : (h == 2) ? 512 : (1 << 30);
    int klo = Q0 - win - 64; if (klo < 0) klo = 0; klo &= ~63;
    const int khi = Q0 + 128;
    const int nsteps = (khi - klo) >> 6;

    __shared__ __align__(16) unsigned short Pl[2][128 * 64];
    __shared__ __align__(16) unsigned short Vl[2][128 * 64];

    const int tid = threadIdx.x, lane = tid & 63, wv = tid >> 6;
    const int wm = (wv >> 1) * 64, wn = (wv & 1) * 64;
    const int l15 = lane & 15, g = lane >> 4;

    f32x4 zero4 = {0.f, 0.f, 0.f, 0.f};
    f32x4 acc[4][4];
#pragma unroll
    for (int i = 0; i < 4; ++i)
#pragma unroll
        for (int j = 0; j < 4; ++j) acc[i][j] = zero4;

    const unsigned short* Ab = P + (((size_t)(h * 2 + b)) * SB + Q0) * SB;
    const unsigned short* Bb = embT + ((size_t)(b * DD + nt * 128)) * SB;

    const unsigned short* Ps[4];
    const unsigned short* Vs[4];
    int ldst[4];
#pragma unroll
    for (int j = 0; j < 4; ++j) {
        int ch = j * 256 + tid;
        int row = ch >> 3, cpos = ch & 7;
        int scol = ((cpos ^ (row & 7)) << 3);
        Ps[j] = Ab + (size_t)row * SB + scol;
        Vs[j] = Bb + (size_t)row * SB + scol;
        ldst[j] = ch * 16;
    }

#define STAGEPV(buf_, k0_) {                                                           \
    _Pragma("unroll")                                                                  \
    for (int j = 0; j < 4; ++j) {                                                      \
        __builtin_amdgcn_global_load_lds(as_gbl(Ps[j] + (k0_)),                        \
            as_lds((char*)Pl[buf_] + ldst[j]), 16, 0, 0);                              \
        __builtin_amdgcn_global_load_lds(as_gbl(Vs[j] + (k0_)),                        \
            as_lds((char*)Vl[buf_] + ldst[j]), 16, 0, 0);                              \
    } }

    STAGEPV(0, klo);
    __syncthreads();
    for (int t = 0; t < nsteps; ++t) {
        const int cur = t & 1;
        if (t + 1 < nsteps) STAGEPV(cur ^ 1, klo + (t + 1) * 64);
#pragma unroll
        for (int s = 0; s < 2; ++s) {
            bf16x8 af[4], bfr[4];
#pragma unroll
            for (int i = 0; i < 4; ++i) {
                af[i]  = ldsrd64(Pl[cur], wm + i * 16 + l15, s * 4 + g);
                bfr[i] = ldsrd64(Vl[cur], wn + i * 16 + l15, s * 4 + g);
            }
#pragma unroll
            for (int i = 0; i < 4; ++i)
#pragma unroll
                for (int j = 0; j < 4; ++j)
                    acc[i][j] = __builtin_amdgcn_mfma_f32_16x16x32_bf16(af[i], bfr[j], acc[i][j], 0, 0, 0);
        }
        __syncthreads();
    }
#undef STAGEPV

    const float* ls = lsum + ((size_t)(h * 2 + b)) * SB;
    unsigned short* cb  = concat + ((size_t)(b * SB)) * (HH * DD) + h * DD + nt * 128;
    unsigned short* cb3 = concat + ((size_t)(b * SB)) * (HH * DD) + 3 * DD + nt * 128;
    const bool wr3 = (h == 0) && dup;
#pragma unroll
    for (int i = 0; i < 4; ++i) {
        int rowb = wm + i * 16 + g * 4;
        float inv[4];
#pragma unroll
        for (int rr = 0; rr < 4; ++rr) inv[rr] = 1.f / ls[Q0 + rowb + rr];
#pragma unroll
        for (int j = 0; j < 4; ++j) {
            int col = wn + j * 16 + l15;
#pragma unroll
            for (int rr = 0; rr < 4; ++rr) {
                unsigned short v = f2bf(acc[i][j][rr] * inv[rr]);
                cb[(size_t)(Q0 + rowb + rr) * (HH * DD) + col] = v;
                if (wr3) cb3[(size_t)(Q0 + rowb + rr) * (HH * DD) + col] = v;
            }
        }
    }
}

// ---------------- fusion GEMM: 128x128, BK=32 double-buffered ----------------
template <int OUTF32>
__launch_bounds__(256, 2)
__global__ void k_gemm_bt(const unsigned short* __restrict__ A,
                          const unsigned short* __restrict__ Bt,
                          const float* __restrict__ bias,
                          void* __restrict__ Cout,
                          int M, int N, int K)
{
    const int nMt = M >> 7;
    const int nwg = gridDim.x;
    int bid = blockIdx.x;
    int q = nwg >> 3, r = nwg & 7;
    int x = bid & 7, o = bid >> 3;
    int wg = (x < r ? x * (q + 1) : r * (q + 1) + (x - r) * q) + o;
    const int mt = wg % nMt, nt = wg / nMt;

    __shared__ __align__(16) unsigned short Al[2][128 * 32];
    __shared__ __align__(16) unsigned short Bl[2][128 * 32];

    const int tid = threadIdx.x;
    const int lane = tid & 63;
    const int wv = tid >> 6;
    const int wm = (wv >> 1) * 64, wn = (wv & 1) * 64;
    const int l15 = lane & 15, g = lane >> 4;

    f32x4 zero4 = {0.f, 0.f, 0.f, 0.f};
    f32x4 acc[4][4];
#pragma unroll
    for (int i = 0; i < 4; ++i)
#pragma unroll
        for (int j = 0; j < 4; ++j) acc[i][j] = zero4;

    const unsigned short* Ab = A + (size_t)mt * 128 * K;
    const unsigned short* Bb = Bt + (size_t)nt * 128 * K;

#define STAGEF(buf_, k0_) {                                                            \
    _Pragma("unroll")                                                                  \
    for (int s = 0; s < 2; ++s) {                                                      \
        int e = (s * 256 + tid) * 8;                                                   \
        int row = e >> 5, col = e & 31;                                                \
        __builtin_amdgcn_global_load_lds(as_gbl(Ab + (size_t)row * K + (k0_) + col),   \
                                         as_lds(Al[buf_] + e), 16, 0, 0);              \
        __builtin_amdgcn_global_load_lds(as_gbl(Bb + (size_t)row * K + (k0_) + col),   \
                                         as_lds(Bl[buf_] + e), 16, 0, 0);              \
    } }

    const int nk = K >> 5;
    STAGEF(0, 0);
    __syncthreads();
    for (int t = 0; t < nk; ++t) {
        const int cur = t & 1;
        if (t + 1 < nk) STAGEF(cur ^ 1, (t + 1) * 32);
        bf16x8 af[4], bfr[4];
#pragma unroll
        for (int i = 0; i < 4; ++i) {
            af[i]  = *(const bf16x8*)(Al[cur] + (wm + i * 16 + l15) * 32 + 8 * g);
            bfr[i] = *(const bf16x8*)(Bl[cur] + (wn + i * 16 + l15) * 32 + 8 * g);
        }
#pragma unroll
        for (int i = 0; i < 4; ++i)
#pragma unroll
            for (int j = 0; j < 4; ++j)
                acc[i][j] = __builtin_amdgcn_mfma_f32_16x16x32_bf16(af[i], bfr[j], acc[i][j], 0, 0, 0);
        __syncthreads();
    }
#undef STAGEF

#pragma unroll
    for (int i = 0; i < 4; ++i) {
        int rowb = mt * 128 + wm + i * 16 + g * 4;
#pragma unroll
        for (int j = 0; j < 4; ++j) {
            int col = nt * 128 + wn + j * 16 + l15;
            float bv = bias[col];
            if (OUTF32) {
                float* C = (float*)Cout;
#pragma unroll
                for (int rr = 0; rr < 4; ++rr)
                    C[(size_t)(rowb + rr) * N + col] = acc[i][j][rr] + bv;
            } else {
                unsigned short* C = (unsigned short*)Cout;
#pragma unroll
                for (int rr = 0; rr < 4; ++rr)
                    C[(size_t)(rowb + rr) * N + col] = f2bf(acc[i][j][rr] + bv);
            }
        }
    }
}

// ---------------- logits GEMM: 256x256 BK=64 dbuf; nt-fastest XCD chunking ----------
__launch_bounds__(512, 1)
__global__ void k_logits(const unsigned short* __restrict__ A,
                         const unsigned short* __restrict__ Bt,
                         const float* __restrict__ bias,
                         float* __restrict__ Cout,
                         int M, int N, int K)
{
    const int nNt = (N + 255) >> 8;       // 125
    const int nwg = gridDim.x;
    int bid = blockIdx.x;
    int q = nwg >> 3, r = nwg & 7;
    int x = bid & 7, o = bid >> 3;
    int wg = (x < r ? x * (q + 1) : r * (q + 1) + (x - r) * q) + o;
    const int nt = wg % nNt, mt = wg / nNt;   // nt-fastest: XCD keeps A-panel L2-resident

    __shared__ __align__(16) char smem[131072];

    const int tid = threadIdx.x, lane = tid & 63, wv = tid >> 6;
    const int wr = wv >> 2, wc = wv & 3;
    const int l15 = lane & 15, g = lane >> 4;

    f32x4 zero4 = {0.f, 0.f, 0.f, 0.f};
    f32x4 acc[8][4];
#pragma unroll
    for (int i = 0; i < 8; ++i)
#pragma unroll
        for (int j = 0; j < 4; ++j) acc[i][j] = zero4;

    const unsigned short* Ab = A + (size_t)mt * 256 * K;
    const unsigned short* Bb = Bt + (size_t)nt * 256 * K;

    const unsigned short* As[4];
    const unsigned short* Bs[4];
    int ldstA[4], ldstB[4];
#pragma unroll
    for (int j = 0; j < 4; ++j) {
        int ch = tid + j * 512;
        int row = ch >> 3, cpos = ch & 7;
        int scol = ((cpos ^ (row & 7)) << 3);
        As[j] = Ab + (size_t)row * K + scol;
        Bs[j] = Bb + (size_t)row * K + scol;
        ldstA[j] = ch * 16;
        ldstB[j] = 65536 + ch * 16;
    }

#define STG(bufi_, k0_) {                                                              \
    _Pragma("unroll")                                                                  \
    for (int j = 0; j < 4; ++j)                                                        \
        __builtin_amdgcn_global_load_lds(as_gbl(As[j] + (k0_)),                        \
            as_lds(smem + (bufi_) * 32768 + ldstA[j]), 16, 0, 0);                      \
    _Pragma("unroll")                                                                  \
    for (int j = 0; j < 4; ++j)                                                        \
        __builtin_amdgcn_global_load_lds(as_gbl(Bs[j] + (k0_)),                        \
            as_lds(smem + (bufi_) * 32768 + ldstB[j]), 16, 0, 0); }

    STG(0, 0);
    __syncthreads();

    for (int t = 0; t < 8; ++t) {
        const int cur = t & 1;
        if (t < 7) STG(cur ^ 1, (t + 1) * 64);
        const unsigned short* Ar = (const unsigned short*)(smem + cur * 32768);
        const unsigned short* Br = (const unsigned short*)(smem + cur * 32768 + 65536);
#pragma unroll
        for (int s = 0; s < 2; ++s) {
            bf16x8 bf[4], af[8];
#pragma unroll
            for (int n = 0; n < 4; ++n)
                bf[n] = ldsrd64(Br, wc * 64 + n * 16 + l15, s * 4 + g);
#pragma unroll
            for (int m = 0; m < 8; ++m)
                af[m] = ldsrd64(Ar, wr * 128 + m * 16 + l15, s * 4 + g);
            __builtin_amdgcn_s_setprio(1);
#pragma unroll
            for (int m = 0; m < 8; ++m)
#pragma unroll
                for (int n = 0; n < 4; ++n)
                    acc[m][n] = __builtin_amdgcn_mfma_f32_16x16x32_bf16(af[m], bf[n], acc[m][n], 0, 0, 0);
            __builtin_amdgcn_s_setprio(0);
        }
        __syncthreads();
    }
#undef STG

    const int mrow = mt * 256;
    const int ncol = nt * 256;
    float* Cl = (float*)smem;
    float bvj[4];
#pragma unroll
    for (int j = 0; j < 4; ++j) bvj[j] = bias[ncol + wc * 64 + j * 16 + l15];
    const int srow = tid >> 4;
    const int scol = (tid & 15) * 4;
    const float* Crd = Cl + srow * 258 + scol;
#pragma unroll
    for (int mc = 0; mc < 8; ++mc) {
        if (wr == (mc >> 2)) {
            int ibase = (mc & 3) * 2;
#pragma unroll
            for (int ii = 0; ii < 2; ++ii) {
                int i = ibase + ii;
                int lr = ii * 16 + g * 4;
#pragma unroll
                for (int j = 0; j < 4; ++j)
#pragma unroll
                    for (int rr = 0; rr < 4; ++rr)
                        Cl[(lr + rr) * 258 + wc * 64 + j * 16 + l15] = acc[i][j][rr] + bvj[j];
            }
        }
        __syncthreads();
        {
            float* gp = Cout + (size_t)(mrow + mc * 32 + srow) * N + ncol + scol;
#pragma unroll
            for (int it = 0; it < 4; ++it)
                *(float4*)(gp + it * 64) = *(const float4*)(Crd + it * 64);
        }
        __syncthreads();
    }
}

extern "C" void kernel_launch(void* const* d_in, const int* in_sizes, int n_in,
                              void* d_out, int out_size, void* d_ws, size_t ws_size,
                              hipStream_t stream)
{
    const int*           ids = (const int*)d_in[0];
    const unsigned char* pad = (const unsigned char*)d_in[1];
    const float*         tbl = (const float*)d_in[2];
    const float*         sfs = (const float*)d_in[3];
    const float*         als = (const float*)d_in[4];
    const float*         fw  = (const float*)d_in[5];
    const float*         fb  = (const float*)d_in[6];
    const float*         ow  = (const float*)d_in[7];
    const float*         ob  = (const float*)d_in[8];
    float* logits = (float*)d_out;

    // d_ws layout (60 MB)
    char* ws = (char*)d_ws;
    unsigned short* outw_bf = (unsigned short*)(ws);              // 32,768,000 B
    unsigned short* fusw_bf = (unsigned short*)(ws + 32768000);   //  2,097,152 B
    unsigned short* emb_bf  = (unsigned short*)(ws + 34865152);   //  4,194,304 B
    unsigned short* concat  = (unsigned short*)(ws + 39059456);   // 16,777,216 B
    unsigned short* fused   = (unsigned short*)(ws + 55836672);   //  4,194,304 B

    // scratch inside d_out (dead until final GEMM overwrites it)
    char* ob_scratch = (char*)d_out;
    unsigned short* P    = (unsigned short*)(ob_scratch);              // 67,108,864 B
    unsigned short* embT = (unsigned short*)(ob_scratch + 67108864);   //  4,194,304 B
    float*          dtab = (float*)(ob_scratch + 71303168);            //     32,768 B
    float*          lsum = (float*)(ob_scratch + 71335936);            //     65,536 B

    k_prep<<<6960, 256, 0, stream>>>(ids, tbl, als, fw, ow,
                                     outw_bf, fusw_bf, emb_bf, embT, dtab, lsum);

    dim3 bg(32, 32, BB);
    k_base<<<bg, 256, 0, stream>>>(emb_bf, pad, sfs, als, dtab, P, lsum);

    dim3 pg(64, BB, HH);
    k_pv<<<pg, 256, 0, stream>>>(P, embT, lsum, sfs, als, concat);

    k_gemm_bt<0><<<32 * 4, 256, 0, stream>>>(concat, fusw_bf, fb, fused, BB * SB, DD, HH * DD);
    k_logits<<<16 * 125, 512, 0, stream>>>(fused, outw_bf, ob, logits, BB * SB, VV, DD);
}